// Round 10
// baseline (413.191 us; speedup 1.0000x reference)
//
#include <hip/hip_runtime.h>

typedef __attribute__((ext_vector_type(8))) short short8;
typedef __attribute__((ext_vector_type(8))) unsigned short us8;
typedef __attribute__((ext_vector_type(4))) unsigned short us4;
typedef __attribute__((ext_vector_type(4))) float f32x4;

static __device__ __forceinline__ unsigned short f2bf(float f) {
  union { float f; unsigned u; } c; c.f = f;
  unsigned r = (c.u + 0x7FFFu + ((c.u >> 16) & 1u)) >> 16;
  return (unsigned short)r;
}
static __device__ __forceinline__ float b2f(unsigned short h) {
  union { unsigned u; float f; } c; c.u = ((unsigned)h) << 16; return c.f;
}

static __device__ __forceinline__ void gll16(const unsigned short* g, unsigned short* l) {
  __builtin_amdgcn_global_load_lds(
      (const __attribute__((address_space(1))) unsigned int*)g,
      (__attribute__((address_space(3))) unsigned int*)l, 16, 0, 0);
}

// ---- wv, wp -> bf16
__global__ __launch_bounds__(256) void conv_k(
    const float* __restrict__ wv, const float* __restrict__ wp,
    unsigned short* __restrict__ wvb, unsigned short* __restrict__ wpb)
{
  int i4 = (blockIdx.x * 256 + threadIdx.x) * 4;
  const float* src;
  unsigned short* dst;
  if (i4 < 262144) { src = wv + i4; dst = wvb + i4; }
  else             { src = wp + (i4 - 262144); dst = wpb + (i4 - 262144); }
  f32x4 v = *(const f32x4*)src;
  us4 o;
  #pragma unroll
  for (int j = 0; j < 4; ++j) o[j] = f2bf(v[j]);
  *(us4*)dst = o;
}

// ---- transpose wq,wk (f32 [512][512]) -> wqT,wkT (bf16 [c][o])
__global__ __launch_bounds__(256) void tk(
    const float* __restrict__ wq, const float* __restrict__ wk,
    unsigned short* __restrict__ wqT, unsigned short* __restrict__ wkT)
{
  __shared__ float L[64][65];
  const float* src = blockIdx.z ? wk : wq;
  unsigned short* dst = blockIdx.z ? wkT : wqT;
  const int ro = blockIdx.x * 64, co = blockIdx.y * 64;
  const int tid = threadIdx.x;
  #pragma unroll
  for (int p = 0; p < 4; ++p) {
    int lin = p * 1024 + tid * 4;
    int r = lin >> 6, cl = lin & 63;
    *(f32x4*)&L[r][cl] = *(const f32x4*)(src + (size_t)(ro + r) * 512 + co + cl);
  }
  __syncthreads();
  #pragma unroll
  for (int p = 0; p < 4; ++p) {
    int lin = p * 1024 + tid * 4;
    int rr = lin >> 6, cc = lin & 63;
    us4 o;
    #pragma unroll
    for (int j = 0; j < 4; ++j) o[j] = f2bf(L[cc + j][rr]);
    *(us4*)(dst + (size_t)(co + rr) * 512 + ro + cc) = o;
  }
}

// ---- w2b[c] = sum_o bq[o] * wk[o][c]
__global__ __launch_bounds__(256) void w2b_k(
    const unsigned short* __restrict__ wkT, const float* __restrict__ bq,
    float* __restrict__ w2b)
{
  const int wv_ = threadIdx.x >> 6, lane = threadIdx.x & 63;
  for (int i = 0; i < 16; ++i) {
    const int c = blockIdx.x * 64 + i * 4 + wv_;
    us8 kv = *(const us8*)(wkT + (size_t)c * 512 + lane * 8);
    float s = 0.f;
    #pragma unroll
    for (int j = 0; j < 8; ++j) s += b2f(kv[j]) * bq[lane * 8 + j];
    #pragma unroll
    for (int o = 32; o; o >>= 1) s += __shfl_xor(s, o);
    if (lane == 0) w2b[c] = s;
  }
}

// ---- GroupNorm -> hT [b][s=256][c=512] bf16
__global__ __launch_bounds__(512) void gn_k(
    const float* __restrict__ x, const float* __restrict__ gw,
    const float* __restrict__ gb, unsigned short* __restrict__ hT)
{
  __shared__ unsigned short tile[32][256];
  __shared__ float rs[2][4][2];
  const int b = blockIdx.x >> 4, gp = blockIdx.x & 15;
  const int tid = threadIdx.x;
  const int sub = tid >> 8;
  const int t = tid & 255;
  const int g = gp * 2 + sub;
  const float* xp = x + ((size_t)b * 512 + g * 16) * 256;
  f32x4 vals[4];
  float s = 0.f, s2 = 0.f;
  #pragma unroll
  for (int j = 0; j < 4; ++j) {
    f32x4 v = *(const f32x4*)(xp + j * 1024 + t * 4);
    vals[j] = v;
    s  += v[0] + v[1] + v[2] + v[3];
    s2 += v[0]*v[0] + v[1]*v[1] + v[2]*v[2] + v[3]*v[3];
  }
  #pragma unroll
  for (int o = 32; o; o >>= 1) { s += __shfl_xor(s, o); s2 += __shfl_xor(s2, o); }
  if ((t & 63) == 0) { rs[sub][t >> 6][0] = s; rs[sub][t >> 6][1] = s2; }
  __syncthreads();
  s  = rs[sub][0][0] + rs[sub][1][0] + rs[sub][2][0] + rs[sub][3][0];
  s2 = rs[sub][0][1] + rs[sub][1][1] + rs[sub][2][1] + rs[sub][3][1];
  const float mean = s * (1.f / 4096.f);
  const float var  = s2 * (1.f / 4096.f) - mean * mean;
  const float rstd = rsqrtf(var + 1e-5f);
  #pragma unroll
  for (int j = 0; j < 4; ++j) {
    const int cl = j * 4 + (t >> 6);
    const int c = g * 16 + cl;
    const float sc = gw[c] * rstd;
    const float sh = gb[c] - mean * sc;
    f32x4 v = vals[j];
    us4 o;
    #pragma unroll
    for (int q = 0; q < 4; ++q) o[q] = f2bf(v[q] * sc + sh);
    *(us4*)&tile[sub * 16 + cl][(t & 63) * 4] = o;
  }
  __syncthreads();
  const int srow = tid >> 1, half = tid & 1;
  us8 o0, o1;
  #pragma unroll
  for (int c = 0; c < 8; ++c) o0[c] = tile[half * 16 + c][srow];
  #pragma unroll
  for (int c = 0; c < 8; ++c) o1[c] = tile[half * 16 + 8 + c][srow];
  unsigned short* dst = hT + ((size_t)b * 256 + srow) * 512 + gp * 32 + half * 16;
  *(us8*)dst = o0;
  *(us8*)(dst + 8) = o1;
}

// ---- pipelined B^T-form GEMM: C[bz][m][n] = sum_k A[m][k]*B[n][k] (+bias)(+resid)
// AREG=true: A-fragments read directly global->register (A small & L2-resident);
//            LDS holds only B (32KB dbuf) -> 3 blocks/CU.
template<int BM, int BN, int MI, int TPB, int NWN, int NTT,
         int BIAS_MODE, bool OUT_F32, bool HAS_RESID, bool NFAST, bool AREG,
         int MINW = 2>
__global__ __launch_bounds__(TPB, MINW) void gemmp_k(
    const unsigned short* __restrict__ A, long long sAb, int lda,
    const unsigned short* __restrict__ B, long long sBb, int ldb,
    void* __restrict__ Cv, long long sCb, int ldc,
    const float* __restrict__ bias, const float* __restrict__ resid)
{
  constexpr int CA = BM * 8 / TPB;
  constexpr int CB = BN * 8 / TPB;
  constexpr int SMSZ = (AREG ? 0 : 2 * BM * 64) + 2 * BN * 64;
  __shared__ unsigned short SMEM[SMSZ];
  unsigned short* AsBase = SMEM;                                   // unused if AREG
  unsigned short* BsBase = SMEM + (AREG ? 0 : 2 * BM * 64);
  const int tid = threadIdx.x;
  const int bz = blockIdx.z;
  const int bm = (NFAST ? blockIdx.y : blockIdx.x) * BM;
  const int bn = (NFAST ? blockIdx.x : blockIdx.y) * BN;
  const int lane = tid & 63, w = tid >> 6;
  const int wr = w / NWN, wc = w % NWN;
  const int lr = lane & 15, lg = lane >> 4;
  const int csw = lr & 7;
  const int ko0 = (lg ^ csw) * 8;
  const int ko1 = ((4 + lg) ^ csw) * 8;

  const unsigned short* Ab = A + (size_t)bz * sAb;
  const unsigned short* aSrc[CA]; int aOff[CA];
  if (!AREG) {
    #pragma unroll
    for (int p = 0; p < CA; ++p) {
      const int id = p * TPB + tid;
      const int row = id >> 3, cc = (id & 7) ^ (row & 7);
      aSrc[p] = Ab + (size_t)(bm + row) * lda + cc * 8;
      aOff[p] = id * 8;
    }
  }
  const unsigned short* bSrc[CB]; int bOff[CB];
  #pragma unroll
  for (int p = 0; p < CB; ++p) {
    const int id = p * TPB + tid;
    const int row = id >> 3, cc = (id & 7) ^ (row & 7);
    bSrc[p] = B + (size_t)bz * sBb + (size_t)(bn + row) * ldb + cc * 8;
    bOff[p] = id * 8;
  }

  f32x4 acc[MI][4];
  #pragma unroll
  for (int i = 0; i < MI; ++i)
    #pragma unroll
    for (int j = 0; j < 4; ++j) acc[i][j] = (f32x4){0.f, 0.f, 0.f, 0.f};

  if (!AREG) {
    #pragma unroll
    for (int p = 0; p < CA; ++p) gll16(aSrc[p], &AsBase[aOff[p]]);
  }
  #pragma unroll
  for (int p = 0; p < CB; ++p) gll16(bSrc[p], &BsBase[bOff[p]]);
  asm volatile("s_waitcnt vmcnt(0)" ::: "memory");
  __builtin_amdgcn_s_barrier();

  #pragma unroll 2
  for (int t = 0; t < NTT; ++t) {
    if (t + 1 < NTT) {
      const int k1 = (t + 1) * 64, sl = (t + 1) & 1;
      if (!AREG) {
        #pragma unroll
        for (int p = 0; p < CA; ++p) gll16(aSrc[p] + k1, &AsBase[sl * BM * 64 + aOff[p]]);
      }
      #pragma unroll
      for (int p = 0; p < CB; ++p) gll16(bSrc[p] + k1, &BsBase[sl * BN * 64 + bOff[p]]);
    }
    const unsigned short* At = &AsBase[(t & 1) * BM * 64];
    const unsigned short* Bt = &BsBase[(t & 1) * BN * 64];
    const int k0 = t * 64;
    short8 bf[4][2];
    #pragma unroll
    for (int nj = 0; nj < 4; ++nj) {
      bf[nj][0] = *(const short8*)(Bt + (wc * 64 + nj * 16 + lr) * 64 + ko0);
      bf[nj][1] = *(const short8*)(Bt + (wc * 64 + nj * 16 + lr) * 64 + ko1);
    }
    #pragma unroll
    for (int h = 0; h < MI / 4; ++h) {
      short8 af[4][2];
      #pragma unroll
      for (int mi = 0; mi < 4; ++mi) {
        const int rr = wr * (MI * 16) + h * 64 + mi * 16 + lr;
        if (AREG) {
          const unsigned short* ap = Ab + (size_t)(bm + rr) * lda + k0;
          af[mi][0] = *(const short8*)(ap + lg * 8);
          af[mi][1] = *(const short8*)(ap + 32 + lg * 8);
        } else {
          af[mi][0] = *(const short8*)(At + rr * 64 + ko0);
          af[mi][1] = *(const short8*)(At + rr * 64 + ko1);
        }
      }
      __builtin_amdgcn_s_setprio(1);
      #pragma unroll
      for (int mi = 0; mi < 4; ++mi)
        #pragma unroll
        for (int nj = 0; nj < 4; ++nj) {
          acc[h * 4 + mi][nj] = __builtin_amdgcn_mfma_f32_16x16x32_bf16(af[mi][0], bf[nj][0], acc[h * 4 + mi][nj], 0, 0, 0);
          acc[h * 4 + mi][nj] = __builtin_amdgcn_mfma_f32_16x16x32_bf16(af[mi][1], bf[nj][1], acc[h * 4 + mi][nj], 0, 0, 0);
        }
      __builtin_amdgcn_s_setprio(0);
    }
    if (t + 1 < NTT) {
      asm volatile("s_waitcnt vmcnt(0)" ::: "memory");
      __builtin_amdgcn_s_barrier();
    }
  }

  #pragma unroll
  for (int mi = 0; mi < MI; ++mi) {
    #pragma unroll
    for (int r = 0; r < 4; ++r) {
      const int rowc = bm + wr * (MI * 16) + mi * 16 + lg * 4 + r;
      const float bv_ = (BIAS_MODE == 1) ? bias[rowc] : 0.f;
      #pragma unroll
      for (int ni = 0; ni < 4; ++ni) {
        const int col = bn + wc * 64 + ni * 16 + lr;
        float vv = acc[mi][ni][r] + bv_;
        if (BIAS_MODE == 2) vv += bias[col];
        const size_t idx = (size_t)bz * sCb + (size_t)rowc * ldc + col;
        if (HAS_RESID) vv += resid[idx];
        if (OUT_F32) ((float*)Cv)[idx] = vv;
        else ((unsigned short*)Cv)[idx] = f2bf(vv);
      }
    }
  }
}

// ---- 256x256 GEMM + fused row-softmax (G2)
template<int NT>
__global__ __launch_bounds__(512, 2) void gemm3_k(
    const unsigned short* __restrict__ A, long long sAb, int lda,
    const unsigned short* __restrict__ B, long long sBb, int ldb,
    unsigned short* __restrict__ Cb_, long long sCb, int ldc)
{
  __shared__ unsigned short As[4][8192];
  __shared__ unsigned short Bs[4][8192];
  const int tid = threadIdx.x;
  const int bz = blockIdx.z;
  const int lane = tid & 63, w = tid >> 6;
  const int wr = w >> 2, wc = w & 3;
  const int lr = lane & 15, lg = lane >> 4;
  const int csw = lr & 7;
  const int ko0 = (lg ^ csw) * 8;
  const int ko1 = ((4 + lg) ^ csw) * 8;

  const int rl = tid >> 3;
  const int gc = (tid & 7) ^ (rl & 7);
  const unsigned short* pA = A + (size_t)bz * sAb + (size_t)rl * lda + gc * 8;
  const unsigned short* pB = B + (size_t)bz * sBb + (size_t)rl * ldb + gc * 8;

  auto stageA = [&](int t, int h) {
    const unsigned short* s = pA + (size_t)h * 128 * lda + t * 64;
    unsigned short* d = &As[(2 * t + h) & 3][tid * 8];
    gll16(s, d);
    gll16(s + (size_t)64 * lda, d + 4096);
  };
  auto stageB = [&](int t, int h) {
    const unsigned short* s = pB + (size_t)h * 128 * ldb + t * 64;
    unsigned short* d = &Bs[(2 * t + h) & 3][tid * 8];
    gll16(s, d);
    gll16(s + (size_t)64 * ldb, d + 4096);
  };

  f32x4 acc[8][4];
  #pragma unroll
  for (int i = 0; i < 8; ++i)
    #pragma unroll
    for (int j = 0; j < 4; ++j) acc[i][j] = (f32x4){0.f, 0.f, 0.f, 0.f};

  stageA(0, 0); stageA(0, 1); stageB(0, 0); stageB(0, 1);
  stageB(1, 0); stageA(1, 0); stageA(1, 1);
  asm volatile("s_waitcnt vmcnt(6)" ::: "memory");
  __builtin_amdgcn_s_barrier();

  for (int t = 0; t < NT; ++t) {
    const unsigned short* sA = &As[(2 * t + wr) & 3][0];
    const unsigned short* sB = &Bs[(2 * t + (wc >> 1)) & 3][0];
    const int bc = (wc & 1) * 64;
    short8 af[4][2], bf0[2][2], bf1[2][2];

    #pragma unroll
    for (int mi = 0; mi < 4; ++mi) {
      af[mi][0] = *(const short8*)(sA + (mi * 16 + lr) * 64 + ko0);
      af[mi][1] = *(const short8*)(sA + (mi * 16 + lr) * 64 + ko1);
    }
    #pragma unroll
    for (int nj = 0; nj < 2; ++nj) {
      bf0[nj][0] = *(const short8*)(sB + (bc + nj * 16 + lr) * 64 + ko0);
      bf0[nj][1] = *(const short8*)(sB + (bc + nj * 16 + lr) * 64 + ko1);
    }
    if (t + 1 < NT) stageB(t + 1, 1);
    __builtin_amdgcn_s_barrier();
    __builtin_amdgcn_s_setprio(1);
    #pragma unroll
    for (int mi = 0; mi < 4; ++mi)
      #pragma unroll
      for (int nj = 0; nj < 2; ++nj) {
        acc[mi][nj] = __builtin_amdgcn_mfma_f32_16x16x32_bf16(af[mi][0], bf0[nj][0], acc[mi][nj], 0, 0, 0);
        acc[mi][nj] = __builtin_amdgcn_mfma_f32_16x16x32_bf16(af[mi][1], bf0[nj][1], acc[mi][nj], 0, 0, 0);
      }
    __builtin_amdgcn_s_setprio(0);
    __builtin_amdgcn_s_barrier();

    #pragma unroll
    for (int nj = 0; nj < 2; ++nj) {
      bf1[nj][0] = *(const short8*)(sB + (bc + 32 + nj * 16 + lr) * 64 + ko0);
      bf1[nj][1] = *(const short8*)(sB + (bc + 32 + nj * 16 + lr) * 64 + ko1);
    }
    __builtin_amdgcn_s_barrier();
    __builtin_amdgcn_s_setprio(1);
    #pragma unroll
    for (int mi = 0; mi < 4; ++mi)
      #pragma unroll
      for (int nj = 0; nj < 2; ++nj) {
        acc[mi][2 + nj] = __builtin_amdgcn_mfma_f32_16x16x32_bf16(af[mi][0], bf1[nj][0], acc[mi][2 + nj], 0, 0, 0);
        acc[mi][2 + nj] = __builtin_amdgcn_mfma_f32_16x16x32_bf16(af[mi][1], bf1[nj][1], acc[mi][2 + nj], 0, 0, 0);
      }
    __builtin_amdgcn_s_setprio(0);
    __builtin_amdgcn_s_barrier();

    #pragma unroll
    for (int mi = 0; mi < 4; ++mi) {
      af[mi][0] = *(const short8*)(sA + (64 + mi * 16 + lr) * 64 + ko0);
      af[mi][1] = *(const short8*)(sA + (64 + mi * 16 + lr) * 64 + ko1);
    }
    if (t + 2 < NT) stageB(t + 2, 0);
    __builtin_amdgcn_s_barrier();
    __builtin_amdgcn_s_setprio(1);
    #pragma unroll
    for (int mi = 0; mi < 4; ++mi)
      #pragma unroll
      for (int nj = 0; nj < 2; ++nj) {
        acc[4 + mi][nj] = __builtin_amdgcn_mfma_f32_16x16x32_bf16(af[mi][0], bf0[nj][0], acc[4 + mi][nj], 0, 0, 0);
        acc[4 + mi][nj] = __builtin_amdgcn_mfma_f32_16x16x32_bf16(af[mi][1], bf0[nj][1], acc[4 + mi][nj], 0, 0, 0);
      }
    __builtin_amdgcn_s_setprio(0);
    __builtin_amdgcn_s_barrier();

    if (t + 2 < NT) { stageA(t + 2, 0); stageA(t + 2, 1); }
    __builtin_amdgcn_s_barrier();
    __builtin_amdgcn_s_setprio(1);
    #pragma unroll
    for (int mi = 0; mi < 4; ++mi)
      #pragma unroll
      for (int nj = 0; nj < 2; ++nj) {
        acc[4 + mi][2 + nj] = __builtin_amdgcn_mfma_f32_16x16x32_bf16(af[mi][0], bf1[nj][0], acc[4 + mi][2 + nj], 0, 0, 0);
        acc[4 + mi][2 + nj] = __builtin_amdgcn_mfma_f32_16x16x32_bf16(af[mi][1], bf1[nj][1], acc[4 + mi][2 + nj], 0, 0, 0);
      }
    __builtin_amdgcn_s_setprio(0);
    if (t == NT - 2)      asm volatile("s_waitcnt vmcnt(0)" ::: "memory");
    else if (t < NT - 2)  asm volatile("s_waitcnt vmcnt(6)" ::: "memory");
    __builtin_amdgcn_s_barrier();
  }

  const float SC = 0.044194173824159216f;
  float* redm = (float*)&As[0][0];
  float* reds = redm + 1024;
  float rmax[8][4];
  #pragma unroll
  for (int mi = 0; mi < 8; ++mi)
    #pragma unroll
    for (int r = 0; r < 4; ++r) {
      float m = fmaxf(fmaxf(acc[mi][0][r], acc[mi][1][r]),
                      fmaxf(acc[mi][2][r], acc[mi][3][r]));
      #pragma unroll
      for (int o = 1; o <= 8; o <<= 1) m = fmaxf(m, __shfl_xor(m, o));
      rmax[mi][r] = m;
    }
  __syncthreads();
  if (lr == 0) {
    #pragma unroll
    for (int mi = 0; mi < 8; ++mi)
      #pragma unroll
      for (int r = 0; r < 4; ++r)
        redm[(wr * 128 + mi * 16 + lg * 4 + r) * 4 + wc] = rmax[mi][r];
  }
  __syncthreads();
  float rsum[8][4];
  #pragma unroll
  for (int mi = 0; mi < 8; ++mi)
    #pragma unroll
    for (int r = 0; r < 4; ++r) {
      const int row = wr * 128 + mi * 16 + lg * 4 + r;
      f32x4 q = *(const f32x4*)&redm[row * 4];
      const float m = fmaxf(fmaxf(q[0], q[1]), fmaxf(q[2], q[3]));
      float s = 0.f;
      #pragma unroll
      for (int ni = 0; ni < 4; ++ni) {
        float e = __expf((acc[mi][ni][r] - m) * SC);
        acc[mi][ni][r] = e;
        s += e;
      }
      #pragma unroll
      for (int o = 1; o <= 8; o <<= 1) s += __shfl_xor(s, o);
      rsum[mi][r] = s;
    }
  if (lr == 0) {
    #pragma unroll
    for (int mi = 0; mi < 8; ++mi)
      #pragma unroll
      for (int r = 0; r < 4; ++r)
        reds[(wr * 128 + mi * 16 + lg * 4 + r) * 4 + wc] = rsum[mi][r];
  }
  __syncthreads();
  unsigned short* Cb = Cb_ + (size_t)bz * sCb;
  #pragma unroll
  for (int mi = 0; mi < 8; ++mi)
    #pragma unroll
    for (int r = 0; r < 4; ++r) {
      const int row = wr * 128 + mi * 16 + lg * 4 + r;
      f32x4 q = *(const f32x4*)&reds[row * 4];
      const float inv = 1.f / (q[0] + q[1] + q[2] + q[3]);
      #pragma unroll
      for (int ni = 0; ni < 4; ++ni) {
        const int col = wc * 64 + ni * 16 + lr;
        Cb[(size_t)row * ldc + col] = f2bf(acc[mi][ni][r] * inv);
      }
    }
}

extern "C" void kernel_launch(void* const* d_in, const int* in_sizes, int n_in,
                              void* d_out, int out_size, void* d_ws, size_t ws_size,
                              hipStream_t stream)
{
  const float* x   = (const float*)d_in[0];
  const float* gnw = (const float*)d_in[1];
  const float* gnb = (const float*)d_in[2];
  const float* wq  = (const float*)d_in[3];
  const float* bq  = (const float*)d_in[4];
  const float* wk  = (const float*)d_in[5];
  // bk cancels in softmax
  const float* wv  = (const float*)d_in[7];
  const float* bv  = (const float*)d_in[8];
  const float* wp  = (const float*)d_in[9];
  const float* bp  = (const float*)d_in[10];
  float* out = (float*)d_out;

  char* ws = (char*)d_ws;
  unsigned short* W2T   = (unsigned short*)(ws);                  // [512][512] bf16
  unsigned short* wvb   = (unsigned short*)(ws + 524288);
  unsigned short* wpb   = (unsigned short*)(ws + 1048576);
  unsigned short* wqT   = (unsigned short*)(ws + 1572864);
  unsigned short* wkT   = (unsigned short*)(ws + 2097152);
  float*          w2b   = (float*)(ws + 2621440);
  unsigned short* hT    = (unsigned short*)(ws + 2885632);        // 65536x512 bf16 (reused as oT)
  unsigned short* T1    = (unsigned short*)(ws + 69994496ull);    // 65536x512 bf16
  unsigned short* v     = (unsigned short*)(ws + 137103360ull);   // B*512*256 bf16
  unsigned short* attb  = (unsigned short*)(ws + 204212224ull);   // B*256*256 bf16
  unsigned short* oT    = hT;

  conv_k<<<512, 256, 0, stream>>>(wv, wp, wvb, wpb);
  tk<<<dim3(8, 8, 2), 256, 0, stream>>>(wq, wk, wqT, wkT);
  w2b_k<<<8, 256, 0, stream>>>(wkT, bq, w2b);
  // W2T[d][c] = sum_o wk[o][d]*wq[o][c]
  gemmp_k<128, 128, 4, 256, 2, 8, 0, false, false, false, false><<<dim3(4, 4, 1), 256, 0, stream>>>(
      wkT, 0, 512, wqT, 0, 512, W2T, 0, 512, nullptr, nullptr);
  gn_k<<<4096, 512, 0, stream>>>(x, gnw, gnb, hT);
  // G1 (flat): T1'[s][d] = hT x W2T^T + w2b[d]  (w2b col-bias carries the u-term exactly)
  gemmp_k<256, 256, 8, 512, 4, 8, 2, false, false, true, false><<<dim3(2, 256, 1), 512, 0, stream>>>(
      hT, 0, 512, W2T, 0, 512, T1, 0, 512, w2b, nullptr);
  // G1b (per-batch, AREG): v[b][c][s] = wvb x hT[b]^T + bv
  gemmp_k<128, 128, 4, 256, 2, 8, 1, false, false, false, true, 3><<<dim3(4, 2, 256), 256, 0, stream>>>(
      wvb, 0, 512, hT, 131072, 512, v, 131072, 256, bv, nullptr);
  // G2+softmax: attb[b][s][t] = softmax_t(T1' hT^T / sqrt(512))
  gemm3_k<8><<<dim3(1, 1, 256), 512, 0, stream>>>(
      T1, 131072, 512, hT, 131072, 512, attb, 65536, 256);
  // G3 (per-batch, AREG): oT[b][t][c] = attb[b] x v[b]^T
  gemmp_k<128, 128, 4, 256, 2, 4, 0, false, false, false, true, 3><<<dim3(2, 4, 256), 256, 0, stream>>>(
      attb, 65536, 256, v, 131072, 256, oT, 131072, 512, nullptr, nullptr);
  // G4 (per-batch, AREG): out[b][c][s] = wpb x oT[b]^T + bp + x
  gemmp_k<128, 128, 4, 256, 2, 8, 1, true, true, false, true, 3><<<dim3(4, 2, 256), 256, 0, stream>>>(
      wpb, 0, 512, oT, 131072, 512, out, 131072, 256, bp, x);
}

// Round 11
// 331.832 us; speedup vs baseline: 1.2452x; 1.2452x over previous
//
#include <hip/hip_runtime.h>

typedef __attribute__((ext_vector_type(8))) short short8;
typedef __attribute__((ext_vector_type(8))) unsigned short us8;
typedef __attribute__((ext_vector_type(4))) unsigned short us4;
typedef __attribute__((ext_vector_type(4))) float f32x4;

static __device__ __forceinline__ unsigned short f2bf(float f) {
  union { float f; unsigned u; } c; c.f = f;
  unsigned r = (c.u + 0x7FFFu + ((c.u >> 16) & 1u)) >> 16;
  return (unsigned short)r;
}
static __device__ __forceinline__ float b2f(unsigned short h) {
  union { unsigned u; float f; } c; c.u = ((unsigned)h) << 16; return c.f;
}

static __device__ __forceinline__ void gll16(const unsigned short* g, unsigned short* l) {
  __builtin_amdgcn_global_load_lds(
      (const __attribute__((address_space(1))) unsigned int*)g,
      (__attribute__((address_space(3))) unsigned int*)l, 16, 0, 0);
}

// ---- wv, wp -> bf16
__global__ __launch_bounds__(256) void conv_k(
    const float* __restrict__ wv, const float* __restrict__ wp,
    unsigned short* __restrict__ wvb, unsigned short* __restrict__ wpb)
{
  int i4 = (blockIdx.x * 256 + threadIdx.x) * 4;
  const float* src;
  unsigned short* dst;
  if (i4 < 262144) { src = wv + i4; dst = wvb + i4; }
  else             { src = wp + (i4 - 262144); dst = wpb + (i4 - 262144); }
  f32x4 v = *(const f32x4*)src;
  us4 o;
  #pragma unroll
  for (int j = 0; j < 4; ++j) o[j] = f2bf(v[j]);
  *(us4*)dst = o;
}

// ---- transpose wq,wk (f32 [512][512]) -> wqT,wkT (bf16 [c][o])
__global__ __launch_bounds__(256) void tk(
    const float* __restrict__ wq, const float* __restrict__ wk,
    unsigned short* __restrict__ wqT, unsigned short* __restrict__ wkT)
{
  __shared__ float L[64][65];
  const float* src = blockIdx.z ? wk : wq;
  unsigned short* dst = blockIdx.z ? wkT : wqT;
  const int ro = blockIdx.x * 64, co = blockIdx.y * 64;
  const int tid = threadIdx.x;
  #pragma unroll
  for (int p = 0; p < 4; ++p) {
    int lin = p * 1024 + tid * 4;
    int r = lin >> 6, cl = lin & 63;
    *(f32x4*)&L[r][cl] = *(const f32x4*)(src + (size_t)(ro + r) * 512 + co + cl);
  }
  __syncthreads();
  #pragma unroll
  for (int p = 0; p < 4; ++p) {
    int lin = p * 1024 + tid * 4;
    int rr = lin >> 6, cc = lin & 63;
    us4 o;
    #pragma unroll
    for (int j = 0; j < 4; ++j) o[j] = f2bf(L[cc + j][rr]);
    *(us4*)(dst + (size_t)(co + rr) * 512 + ro + cc) = o;
  }
}

// ---- w2b[c] = sum_o bq[o] * wk[o][c]
__global__ __launch_bounds__(256) void w2b_k(
    const unsigned short* __restrict__ wkT, const float* __restrict__ bq,
    float* __restrict__ w2b)
{
  const int wv_ = threadIdx.x >> 6, lane = threadIdx.x & 63;
  for (int i = 0; i < 16; ++i) {
    const int c = blockIdx.x * 64 + i * 4 + wv_;
    us8 kv = *(const us8*)(wkT + (size_t)c * 512 + lane * 8);
    float s = 0.f;
    #pragma unroll
    for (int j = 0; j < 8; ++j) s += b2f(kv[j]) * bq[lane * 8 + j];
    #pragma unroll
    for (int o = 32; o; o >>= 1) s += __shfl_xor(s, o);
    if (lane == 0) w2b[c] = s;
  }
}

// ---- GroupNorm -> hT [b][s=256][c=512] bf16
__global__ __launch_bounds__(512) void gn_k(
    const float* __restrict__ x, const float* __restrict__ gw,
    const float* __restrict__ gb, unsigned short* __restrict__ hT)
{
  __shared__ unsigned short tile[32][256];
  __shared__ float rs[2][4][2];
  const int b = blockIdx.x >> 4, gp = blockIdx.x & 15;
  const int tid = threadIdx.x;
  const int sub = tid >> 8;
  const int t = tid & 255;
  const int g = gp * 2 + sub;
  const float* xp = x + ((size_t)b * 512 + g * 16) * 256;
  f32x4 vals[4];
  float s = 0.f, s2 = 0.f;
  #pragma unroll
  for (int j = 0; j < 4; ++j) {
    f32x4 v = *(const f32x4*)(xp + j * 1024 + t * 4);
    vals[j] = v;
    s  += v[0] + v[1] + v[2] + v[3];
    s2 += v[0]*v[0] + v[1]*v[1] + v[2]*v[2] + v[3]*v[3];
  }
  #pragma unroll
  for (int o = 32; o; o >>= 1) { s += __shfl_xor(s, o); s2 += __shfl_xor(s2, o); }
  if ((t & 63) == 0) { rs[sub][t >> 6][0] = s; rs[sub][t >> 6][1] = s2; }
  __syncthreads();
  s  = rs[sub][0][0] + rs[sub][1][0] + rs[sub][2][0] + rs[sub][3][0];
  s2 = rs[sub][0][1] + rs[sub][1][1] + rs[sub][2][1] + rs[sub][3][1];
  const float mean = s * (1.f / 4096.f);
  const float var  = s2 * (1.f / 4096.f) - mean * mean;
  const float rstd = rsqrtf(var + 1e-5f);
  #pragma unroll
  for (int j = 0; j < 4; ++j) {
    const int cl = j * 4 + (t >> 6);
    const int c = g * 16 + cl;
    const float sc = gw[c] * rstd;
    const float sh = gb[c] - mean * sc;
    f32x4 v = vals[j];
    us4 o;
    #pragma unroll
    for (int q = 0; q < 4; ++q) o[q] = f2bf(v[q] * sc + sh);
    *(us4*)&tile[sub * 16 + cl][(t & 63) * 4] = o;
  }
  __syncthreads();
  const int srow = tid >> 1, half = tid & 1;
  us8 o0, o1;
  #pragma unroll
  for (int c = 0; c < 8; ++c) o0[c] = tile[half * 16 + c][srow];
  #pragma unroll
  for (int c = 0; c < 8; ++c) o1[c] = tile[half * 16 + 8 + c][srow];
  unsigned short* dst = hT + ((size_t)b * 256 + srow) * 512 + gp * 32 + half * 16;
  *(us8*)dst = o0;
  *(us8*)(dst + 8) = o1;
}

// ---- pipelined B^T-form GEMM (r9 engine): C[bz][m][n] = sum_k A[m][k]*B[n][k] (+bias)(+resid)
template<int BM, int BN, int MI, int TPB, int NWN, int NTT,
         int BIAS_MODE, bool OUT_F32, bool HAS_RESID, bool NFAST>
__global__ __launch_bounds__(TPB, 2) void gemmp_k(
    const unsigned short* __restrict__ A, long long sAb, int lda,
    const unsigned short* __restrict__ B, long long sBb, int ldb,
    void* __restrict__ Cv, long long sCb, int ldc,
    const float* __restrict__ bias, const float* __restrict__ resid)
{
  constexpr int CA = BM * 8 / TPB;
  constexpr int CB = BN * 8 / TPB;
  __shared__ unsigned short SMEM[2 * BM * 64 + 2 * BN * 64];
  unsigned short* AsBase = SMEM;
  unsigned short* BsBase = SMEM + 2 * BM * 64;
  const int tid = threadIdx.x;
  const int bz = blockIdx.z;
  const int bm = (NFAST ? blockIdx.y : blockIdx.x) * BM;
  const int bn = (NFAST ? blockIdx.x : blockIdx.y) * BN;
  const int lane = tid & 63, w = tid >> 6;
  const int wr = w / NWN, wc = w % NWN;
  const int lr = lane & 15, lg = lane >> 4;
  const int csw = lr & 7;
  const int ko0 = (lg ^ csw) * 8;
  const int ko1 = ((4 + lg) ^ csw) * 8;

  const unsigned short* aSrc[CA]; int aOff[CA];
  #pragma unroll
  for (int p = 0; p < CA; ++p) {
    const int id = p * TPB + tid;
    const int row = id >> 3, cc = (id & 7) ^ (row & 7);
    aSrc[p] = A + (size_t)bz * sAb + (size_t)(bm + row) * lda + cc * 8;
    aOff[p] = id * 8;
  }
  const unsigned short* bSrc[CB]; int bOff[CB];
  #pragma unroll
  for (int p = 0; p < CB; ++p) {
    const int id = p * TPB + tid;
    const int row = id >> 3, cc = (id & 7) ^ (row & 7);
    bSrc[p] = B + (size_t)bz * sBb + (size_t)(bn + row) * ldb + cc * 8;
    bOff[p] = id * 8;
  }

  f32x4 acc[MI][4];
  #pragma unroll
  for (int i = 0; i < MI; ++i)
    #pragma unroll
    for (int j = 0; j < 4; ++j) acc[i][j] = (f32x4){0.f, 0.f, 0.f, 0.f};

  #pragma unroll
  for (int p = 0; p < CA; ++p) gll16(aSrc[p], &AsBase[aOff[p]]);
  #pragma unroll
  for (int p = 0; p < CB; ++p) gll16(bSrc[p], &BsBase[bOff[p]]);
  asm volatile("s_waitcnt vmcnt(0)" ::: "memory");
  __builtin_amdgcn_s_barrier();

  #pragma unroll 2
  for (int t = 0; t < NTT; ++t) {
    if (t + 1 < NTT) {
      const int k1 = (t + 1) * 64, sl = (t + 1) & 1;
      #pragma unroll
      for (int p = 0; p < CA; ++p) gll16(aSrc[p] + k1, &AsBase[sl * BM * 64 + aOff[p]]);
      #pragma unroll
      for (int p = 0; p < CB; ++p) gll16(bSrc[p] + k1, &BsBase[sl * BN * 64 + bOff[p]]);
    }
    const unsigned short* At = &AsBase[(t & 1) * BM * 64];
    const unsigned short* Bt = &BsBase[(t & 1) * BN * 64];
    short8 bf[4][2];
    #pragma unroll
    for (int nj = 0; nj < 4; ++nj) {
      bf[nj][0] = *(const short8*)(Bt + (wc * 64 + nj * 16 + lr) * 64 + ko0);
      bf[nj][1] = *(const short8*)(Bt + (wc * 64 + nj * 16 + lr) * 64 + ko1);
    }
    #pragma unroll
    for (int h = 0; h < MI / 4; ++h) {
      short8 af[4][2];
      #pragma unroll
      for (int mi = 0; mi < 4; ++mi) {
        const int rr = wr * (MI * 16) + h * 64 + mi * 16 + lr;
        af[mi][0] = *(const short8*)(At + rr * 64 + ko0);
        af[mi][1] = *(const short8*)(At + rr * 64 + ko1);
      }
      __builtin_amdgcn_s_setprio(1);
      #pragma unroll
      for (int mi = 0; mi < 4; ++mi)
        #pragma unroll
        for (int nj = 0; nj < 4; ++nj) {
          acc[h * 4 + mi][nj] = __builtin_amdgcn_mfma_f32_16x16x32_bf16(af[mi][0], bf[nj][0], acc[h * 4 + mi][nj], 0, 0, 0);
          acc[h * 4 + mi][nj] = __builtin_amdgcn_mfma_f32_16x16x32_bf16(af[mi][1], bf[nj][1], acc[h * 4 + mi][nj], 0, 0, 0);
        }
      __builtin_amdgcn_s_setprio(0);
    }
    if (t + 1 < NTT) {
      asm volatile("s_waitcnt vmcnt(0)" ::: "memory");
      __builtin_amdgcn_s_barrier();
    }
  }

  #pragma unroll
  for (int mi = 0; mi < MI; ++mi) {
    #pragma unroll
    for (int r = 0; r < 4; ++r) {
      const int rowc = bm + wr * (MI * 16) + mi * 16 + lg * 4 + r;
      const float bv_ = (BIAS_MODE == 1) ? bias[rowc] : 0.f;
      #pragma unroll
      for (int ni = 0; ni < 4; ++ni) {
        const int col = bn + wc * 64 + ni * 16 + lr;
        float vv = acc[mi][ni][r] + bv_;
        if (BIAS_MODE == 2) vv += bias[col];
        const size_t idx = (size_t)bz * sCb + (size_t)rowc * ldc + col;
        if (HAS_RESID) vv += resid[idx];
        if (OUT_F32) ((float*)Cv)[idx] = vv;
        else ((unsigned short*)Cv)[idx] = f2bf(vv);
      }
    }
  }
}

// ---- FUSED G2+G3: per batch, att = softmax(T1' hT^T / sqrt(512)) kept in LDS,
// then oT[b][t][c] = att x v[b]^T. QK phase = proven gemm3 structure.
__global__ __launch_bounds__(512, 1) void fused_k(
    const unsigned short* __restrict__ A,   // T1' [b][256][512]
    const unsigned short* __restrict__ B,   // hT  [b][256][512]
    const unsigned short* __restrict__ V,   // v   [b][512][256]
    unsigned short* __restrict__ O)         // oT  [b][256][512]
{
  __shared__ __attribute__((aligned(16))) char SM[147456];   // 144 KB
  unsigned short* AsB = (unsigned short*)SM;                 // QK: 4 slots x 16KB
  unsigned short* BsB = (unsigned short*)(SM + 65536);       // QK: 4 slots x 16KB
  unsigned short* attL = (unsigned short*)SM;                // PV: [256][256] swizzled (aliases QK bufs)
  unsigned short* vbuf = (unsigned short*)(SM + 131072);     // PV: [128][64]
  float* redm = (float*)(SM + 131072);                       // softmax scratch (dead before vbuf use)
  float* reds = redm + 1024;

  const int tid = threadIdx.x;
  const int bz = blockIdx.z;
  const int lane = tid & 63, w = tid >> 6;
  const int wr = w >> 2, wc = w & 3;
  const int lr = lane & 15, lg = lane >> 4;
  const int csw = lr & 7;
  const int ko0 = (lg ^ csw) * 8;
  const int ko1 = ((4 + lg) ^ csw) * 8;

  const int rl = tid >> 3;
  const int gc = (tid & 7) ^ (rl & 7);
  const unsigned short* pA = A + (size_t)bz * 131072 + (size_t)rl * 512 + gc * 8;
  const unsigned short* pB = B + (size_t)bz * 131072 + (size_t)rl * 512 + gc * 8;

  auto stageA = [&](int t, int h) {
    const unsigned short* s = pA + (size_t)h * 65536 + t * 64;
    unsigned short* d = AsB + ((2 * t + h) & 3) * 8192 + tid * 8;
    gll16(s, d);
    gll16(s + 32768, d + 4096);
  };
  auto stageB = [&](int t, int h) {
    const unsigned short* s = pB + (size_t)h * 65536 + t * 64;
    unsigned short* d = BsB + ((2 * t + h) & 3) * 8192 + tid * 8;
    gll16(s, d);
    gll16(s + 32768, d + 4096);
  };

  f32x4 acc[8][4];
  #pragma unroll
  for (int i = 0; i < 8; ++i)
    #pragma unroll
    for (int j = 0; j < 4; ++j) acc[i][j] = (f32x4){0.f, 0.f, 0.f, 0.f};

  stageA(0, 0); stageA(0, 1); stageB(0, 0); stageB(0, 1);
  stageB(1, 0); stageA(1, 0); stageA(1, 1);
  asm volatile("s_waitcnt vmcnt(6)" ::: "memory");
  __builtin_amdgcn_s_barrier();

  constexpr int NT = 8;
  for (int t = 0; t < NT; ++t) {
    const unsigned short* sA = AsB + ((2 * t + wr) & 3) * 8192;
    const unsigned short* sB = BsB + ((2 * t + (wc >> 1)) & 3) * 8192;
    const int bc = (wc & 1) * 64;
    short8 af[4][2], bf0[2][2], bf1[2][2];

    #pragma unroll
    for (int mi = 0; mi < 4; ++mi) {
      af[mi][0] = *(const short8*)(sA + (mi * 16 + lr) * 64 + ko0);
      af[mi][1] = *(const short8*)(sA + (mi * 16 + lr) * 64 + ko1);
    }
    #pragma unroll
    for (int nj = 0; nj < 2; ++nj) {
      bf0[nj][0] = *(const short8*)(sB + (bc + nj * 16 + lr) * 64 + ko0);
      bf0[nj][1] = *(const short8*)(sB + (bc + nj * 16 + lr) * 64 + ko1);
    }
    if (t + 1 < NT) stageB(t + 1, 1);
    __builtin_amdgcn_s_barrier();
    __builtin_amdgcn_s_setprio(1);
    #pragma unroll
    for (int mi = 0; mi < 4; ++mi)
      #pragma unroll
      for (int nj = 0; nj < 2; ++nj) {
        acc[mi][nj] = __builtin_amdgcn_mfma_f32_16x16x32_bf16(af[mi][0], bf0[nj][0], acc[mi][nj], 0, 0, 0);
        acc[mi][nj] = __builtin_amdgcn_mfma_f32_16x16x32_bf16(af[mi][1], bf0[nj][1], acc[mi][nj], 0, 0, 0);
      }
    __builtin_amdgcn_s_setprio(0);
    __builtin_amdgcn_s_barrier();

    #pragma unroll
    for (int nj = 0; nj < 2; ++nj) {
      bf1[nj][0] = *(const short8*)(sB + (bc + 32 + nj * 16 + lr) * 64 + ko0);
      bf1[nj][1] = *(const short8*)(sB + (bc + 32 + nj * 16 + lr) * 64 + ko1);
    }
    __builtin_amdgcn_s_barrier();
    __builtin_amdgcn_s_setprio(1);
    #pragma unroll
    for (int mi = 0; mi < 4; ++mi)
      #pragma unroll
      for (int nj = 0; nj < 2; ++nj) {
        acc[mi][2 + nj] = __builtin_amdgcn_mfma_f32_16x16x32_bf16(af[mi][0], bf1[nj][0], acc[mi][2 + nj], 0, 0, 0);
        acc[mi][2 + nj] = __builtin_amdgcn_mfma_f32_16x16x32_bf16(af[mi][1], bf1[nj][1], acc[mi][2 + nj], 0, 0, 0);
      }
    __builtin_amdgcn_s_setprio(0);
    __builtin_amdgcn_s_barrier();

    #pragma unroll
    for (int mi = 0; mi < 4; ++mi) {
      af[mi][0] = *(const short8*)(sA + (64 + mi * 16 + lr) * 64 + ko0);
      af[mi][1] = *(const short8*)(sA + (64 + mi * 16 + lr) * 64 + ko1);
    }
    if (t + 2 < NT) stageB(t + 2, 0);
    __builtin_amdgcn_s_barrier();
    __builtin_amdgcn_s_setprio(1);
    #pragma unroll
    for (int mi = 0; mi < 4; ++mi)
      #pragma unroll
      for (int nj = 0; nj < 2; ++nj) {
        acc[4 + mi][nj] = __builtin_amdgcn_mfma_f32_16x16x32_bf16(af[mi][0], bf0[nj][0], acc[4 + mi][nj], 0, 0, 0);
        acc[4 + mi][nj] = __builtin_amdgcn_mfma_f32_16x16x32_bf16(af[mi][1], bf0[nj][1], acc[4 + mi][nj], 0, 0, 0);
      }
    __builtin_amdgcn_s_setprio(0);
    __builtin_amdgcn_s_barrier();

    if (t + 2 < NT) { stageA(t + 2, 0); stageA(t + 2, 1); }
    __builtin_amdgcn_s_barrier();
    __builtin_amdgcn_s_setprio(1);
    #pragma unroll
    for (int mi = 0; mi < 4; ++mi)
      #pragma unroll
      for (int nj = 0; nj < 2; ++nj) {
        acc[4 + mi][2 + nj] = __builtin_amdgcn_mfma_f32_16x16x32_bf16(af[mi][0], bf1[nj][0], acc[4 + mi][2 + nj], 0, 0, 0);
        acc[4 + mi][2 + nj] = __builtin_amdgcn_mfma_f32_16x16x32_bf16(af[mi][1], bf1[nj][1], acc[4 + mi][2 + nj], 0, 0, 0);
      }
    __builtin_amdgcn_s_setprio(0);
    if (t == NT - 2)      asm volatile("s_waitcnt vmcnt(0)" ::: "memory");
    else if (t < NT - 2)  asm volatile("s_waitcnt vmcnt(6)" ::: "memory");
    __builtin_amdgcn_s_barrier();
  }

  // ---- softmax (reductions in SM+131072 scratch)
  const float SC = 0.044194173824159216f;
  float rmax[8][4];
  #pragma unroll
  for (int mi = 0; mi < 8; ++mi)
    #pragma unroll
    for (int r = 0; r < 4; ++r) {
      float m = fmaxf(fmaxf(acc[mi][0][r], acc[mi][1][r]),
                      fmaxf(acc[mi][2][r], acc[mi][3][r]));
      #pragma unroll
      for (int o = 1; o <= 8; o <<= 1) m = fmaxf(m, __shfl_xor(m, o));
      rmax[mi][r] = m;
    }
  __syncthreads();
  if (lr == 0) {
    #pragma unroll
    for (int mi = 0; mi < 8; ++mi)
      #pragma unroll
      for (int r = 0; r < 4; ++r)
        redm[(wr * 128 + mi * 16 + lg * 4 + r) * 4 + wc] = rmax[mi][r];
  }
  __syncthreads();
  float rsum[8][4];
  #pragma unroll
  for (int mi = 0; mi < 8; ++mi)
    #pragma unroll
    for (int r = 0; r < 4; ++r) {
      const int row = wr * 128 + mi * 16 + lg * 4 + r;
      f32x4 q = *(const f32x4*)&redm[row * 4];
      const float m = fmaxf(fmaxf(q[0], q[1]), fmaxf(q[2], q[3]));
      float s = 0.f;
      #pragma unroll
      for (int ni = 0; ni < 4; ++ni) {
        float e = __expf((acc[mi][ni][r] - m) * SC);
        acc[mi][ni][r] = e;
        s += e;
      }
      #pragma unroll
      for (int o = 1; o <= 8; o <<= 1) s += __shfl_xor(s, o);
      rsum[mi][r] = s;
    }
  if (lr == 0) {
    #pragma unroll
    for (int mi = 0; mi < 8; ++mi)
      #pragma unroll
      for (int r = 0; r < 4; ++r)
        reds[(wr * 128 + mi * 16 + lg * 4 + r) * 4 + wc] = rsum[mi][r];
  }
  __syncthreads();

  // ---- write probabilities to attL [256 t][256 s] (XOR-chunk A-fragment layout)
  #pragma unroll
  for (int mi = 0; mi < 8; ++mi)
    #pragma unroll
    for (int r = 0; r < 4; ++r) {
      const int trow = wr * 128 + mi * 16 + lg * 4 + r;
      f32x4 q = *(const f32x4*)&reds[trow * 4];
      const float inv = 1.f / (q[0] + q[1] + q[2] + q[3]);
      const int t7 = trow & 7;
      #pragma unroll
      for (int ni = 0; ni < 4; ++ni) {
        const int cw = ni * 2 + (lr >> 3);            // chunk within 64-window
        const int off = trow * 256 + wc * 64 + ((cw ^ t7) << 3) + (lr & 7);
        attL[off] = f2bf(acc[mi][ni][r] * inv);
      }
    }
  __syncthreads();

  // ---- PV: oT[t][c] = sum_s att[t][s] v[c][s]; 4 col-passes x 4 K-steps
  const unsigned short* Vb = V + (size_t)bz * 131072;
  unsigned short* Ob = O + (size_t)bz * 131072;
  const int vrow = tid >> 3;                           // stage: [128 c][64 s]
  const int vgc = (tid & 7) ^ (vrow & 7);
  for (int pass = 0; pass < 4; ++pass) {
    f32x4 po[8][2];
    #pragma unroll
    for (int i = 0; i < 8; ++i)
      #pragma unroll
      for (int j = 0; j < 2; ++j) po[i][j] = (f32x4){0.f, 0.f, 0.f, 0.f};
    for (int kt = 0; kt < 4; ++kt) {
      #pragma unroll
      for (int p = 0; p < 2; ++p) {
        const int id = p * 512 + tid;
        const int rowv = p * 64 + vrow;
        gll16(Vb + (size_t)(pass * 128 + rowv) * 256 + kt * 64 + vgc * 8,
              vbuf + id * 8);
      }
      asm volatile("s_waitcnt vmcnt(0)" ::: "memory");
      __builtin_amdgcn_s_barrier();
      short8 bfv[2][2];
      #pragma unroll
      for (int nj = 0; nj < 2; ++nj) {
        bfv[nj][0] = *(const short8*)(vbuf + (wc * 32 + nj * 16 + lr) * 64 + ko0);
        bfv[nj][1] = *(const short8*)(vbuf + (wc * 32 + nj * 16 + lr) * 64 + ko1);
      }
      __builtin_amdgcn_s_setprio(1);
      #pragma unroll
      for (int mi = 0; mi < 8; ++mi) {
        const int trow = wr * 128 + mi * 16 + lr;
        const int t7 = trow & 7;
        const unsigned short* ap = attL + trow * 256 + kt * 64;
        short8 afv0 = *(const short8*)(ap + ((lg ^ t7) << 3));
        short8 afv1 = *(const short8*)(ap + (((4 + lg) ^ t7) << 3));
        #pragma unroll
        for (int nj = 0; nj < 2; ++nj) {
          po[mi][nj] = __builtin_amdgcn_mfma_f32_16x16x32_bf16(afv0, bfv[nj][0], po[mi][nj], 0, 0, 0);
          po[mi][nj] = __builtin_amdgcn_mfma_f32_16x16x32_bf16(afv1, bfv[nj][1], po[mi][nj], 0, 0, 0);
        }
      }
      __builtin_amdgcn_s_setprio(0);
      __builtin_amdgcn_s_barrier();
    }
    #pragma unroll
    for (int mi = 0; mi < 8; ++mi)
      #pragma unroll
      for (int r = 0; r < 4; ++r) {
        const int trow = wr * 128 + mi * 16 + lg * 4 + r;
        #pragma unroll
        for (int nj = 0; nj < 2; ++nj) {
          const int c = pass * 128 + wc * 32 + nj * 16 + lr;
          Ob[(size_t)trow * 512 + c] = f2bf(po[mi][nj][r]);
        }
      }
  }
}

extern "C" void kernel_launch(void* const* d_in, const int* in_sizes, int n_in,
                              void* d_out, int out_size, void* d_ws, size_t ws_size,
                              hipStream_t stream)
{
  const float* x   = (const float*)d_in[0];
  const float* gnw = (const float*)d_in[1];
  const float* gnb = (const float*)d_in[2];
  const float* wq  = (const float*)d_in[3];
  const float* bq  = (const float*)d_in[4];
  const float* wk  = (const float*)d_in[5];
  // bk cancels in softmax
  const float* wv  = (const float*)d_in[7];
  const float* bv  = (const float*)d_in[8];
  const float* wp  = (const float*)d_in[9];
  const float* bp  = (const float*)d_in[10];
  float* out = (float*)d_out;

  char* ws = (char*)d_ws;
  unsigned short* W2T   = (unsigned short*)(ws);                  // [512][512] bf16
  unsigned short* wvb   = (unsigned short*)(ws + 524288);
  unsigned short* wpb   = (unsigned short*)(ws + 1048576);
  unsigned short* wqT   = (unsigned short*)(ws + 1572864);
  unsigned short* wkT   = (unsigned short*)(ws + 2097152);
  float*          w2b   = (float*)(ws + 2621440);
  unsigned short* hT    = (unsigned short*)(ws + 2885632);        // 65536x512 bf16 (reused as oT)
  unsigned short* T1    = (unsigned short*)(ws + 69994496ull);    // 65536x512 bf16
  unsigned short* v     = (unsigned short*)(ws + 137103360ull);   // B*512*256 bf16
  unsigned short* oT    = hT;

  conv_k<<<512, 256, 0, stream>>>(wv, wp, wvb, wpb);
  tk<<<dim3(8, 8, 2), 256, 0, stream>>>(wq, wk, wqT, wkT);
  w2b_k<<<8, 256, 0, stream>>>(wkT, bq, w2b);
  // W2T[d][c] = sum_o wk[o][d]*wq[o][c]
  gemmp_k<128, 128, 4, 256, 2, 8, 0, false, false, false><<<dim3(4, 4, 1), 256, 0, stream>>>(
      wkT, 0, 512, wqT, 0, 512, W2T, 0, 512, nullptr, nullptr);
  gn_k<<<4096, 512, 0, stream>>>(x, gnw, gnb, hT);
  // G1 (flat): T1'[s][d] = hT x W2T^T + w2b[d]
  gemmp_k<256, 256, 8, 512, 4, 8, 2, false, false, true><<<dim3(2, 256, 1), 512, 0, stream>>>(
      hT, 0, 512, W2T, 0, 512, T1, 0, 512, w2b, nullptr);
  // G1b (per-batch): v[b][c][s] = wvb x hT[b]^T + bv
  gemmp_k<128, 128, 4, 256, 2, 8, 1, false, false, false><<<dim3(4, 2, 256), 256, 0, stream>>>(
      wvb, 0, 512, hT, 131072, 512, v, 131072, 256, bv, nullptr);
  // FUSED G2+G3: att in LDS, oT[b] = softmax(T1' hT^T) x v^T
  fused_k<<<dim3(1, 1, 256), 512, 0, stream>>>(T1, hT, v, oT);
  // G4 (per-batch): out[b][c][s] = wpb x oT[b]^T + bp + x
  gemmp_k<128, 128, 4, 256, 2, 8, 1, true, true, false><<<dim3(4, 2, 256), 256, 0, stream>>>(
      wpb, 0, 512, oT, 131072, 512, out, 131072, 256, bp, x);
}

// Round 12
// 300.488 us; speedup vs baseline: 1.3751x; 1.1043x over previous
//
#include <hip/hip_runtime.h>

typedef __attribute__((ext_vector_type(8))) short short8;
typedef __attribute__((ext_vector_type(8))) unsigned short us8;
typedef __attribute__((ext_vector_type(4))) unsigned short us4;
typedef __attribute__((ext_vector_type(4))) float f32x4;

static __device__ __forceinline__ unsigned short f2bf(float f) {
  union { float f; unsigned u; } c; c.f = f;
  unsigned r = (c.u + 0x7FFFu + ((c.u >> 16) & 1u)) >> 16;
  return (unsigned short)r;
}
static __device__ __forceinline__ float b2f(unsigned short h) {
  union { unsigned u; float f; } c; c.u = ((unsigned)h) << 16; return c.f;
}

static __device__ __forceinline__ void gll16(const unsigned short* g, unsigned short* l) {
  __builtin_amdgcn_global_load_lds(
      (const __attribute__((address_space(1))) unsigned int*)g,
      (__attribute__((address_space(3))) unsigned int*)l, 16, 0, 0);
}

// ---- wv, wp -> bf16
__global__ __launch_bounds__(256) void conv_k(
    const float* __restrict__ wv, const float* __restrict__ wp,
    unsigned short* __restrict__ wvb, unsigned short* __restrict__ wpb)
{
  int i4 = (blockIdx.x * 256 + threadIdx.x) * 4;
  const float* src;
  unsigned short* dst;
  if (i4 < 262144) { src = wv + i4; dst = wvb + i4; }
  else             { src = wp + (i4 - 262144); dst = wpb + (i4 - 262144); }
  f32x4 v = *(const f32x4*)src;
  us4 o;
  #pragma unroll
  for (int j = 0; j < 4; ++j) o[j] = f2bf(v[j]);
  *(us4*)dst = o;
}

// ---- transpose wq,wk (f32 [512][512]) -> wqT,wkT (bf16 [c][o])
__global__ __launch_bounds__(256) void tk(
    const float* __restrict__ wq, const float* __restrict__ wk,
    unsigned short* __restrict__ wqT, unsigned short* __restrict__ wkT)
{
  __shared__ float L[64][65];
  const float* src = blockIdx.z ? wk : wq;
  unsigned short* dst = blockIdx.z ? wkT : wqT;
  const int ro = blockIdx.x * 64, co = blockIdx.y * 64;
  const int tid = threadIdx.x;
  #pragma unroll
  for (int p = 0; p < 4; ++p) {
    int lin = p * 1024 + tid * 4;
    int r = lin >> 6, cl = lin & 63;
    *(f32x4*)&L[r][cl] = *(const f32x4*)(src + (size_t)(ro + r) * 512 + co + cl);
  }
  __syncthreads();
  #pragma unroll
  for (int p = 0; p < 4; ++p) {
    int lin = p * 1024 + tid * 4;
    int rr = lin >> 6, cc = lin & 63;
    us4 o;
    #pragma unroll
    for (int j = 0; j < 4; ++j) o[j] = f2bf(L[cc + j][rr]);
    *(us4*)(dst + (size_t)(co + rr) * 512 + ro + cc) = o;
  }
}

// ---- w2b[c] = sum_o bq[o] * wk[o][c]
__global__ __launch_bounds__(256) void w2b_k(
    const unsigned short* __restrict__ wkT, const float* __restrict__ bq,
    float* __restrict__ w2b)
{
  const int wv_ = threadIdx.x >> 6, lane = threadIdx.x & 63;
  for (int i = 0; i < 16; ++i) {
    const int c = blockIdx.x * 64 + i * 4 + wv_;
    us8 kv = *(const us8*)(wkT + (size_t)c * 512 + lane * 8);
    float s = 0.f;
    #pragma unroll
    for (int j = 0; j < 8; ++j) s += b2f(kv[j]) * bq[lane * 8 + j];
    #pragma unroll
    for (int o = 32; o; o >>= 1) s += __shfl_xor(s, o);
    if (lane == 0) w2b[c] = s;
  }
}

// ---- GroupNorm -> hT [b][s=256][c=512] bf16
__global__ __launch_bounds__(512) void gn_k(
    const float* __restrict__ x, const float* __restrict__ gw,
    const float* __restrict__ gb, unsigned short* __restrict__ hT)
{
  __shared__ unsigned short tile[32][256];
  __shared__ float rs[2][4][2];
  const int b = blockIdx.x >> 4, gp = blockIdx.x & 15;
  const int tid = threadIdx.x;
  const int sub = tid >> 8;
  const int t = tid & 255;
  const int g = gp * 2 + sub;
  const float* xp = x + ((size_t)b * 512 + g * 16) * 256;
  f32x4 vals[4];
  float s = 0.f, s2 = 0.f;
  #pragma unroll
  for (int j = 0; j < 4; ++j) {
    f32x4 v = *(const f32x4*)(xp + j * 1024 + t * 4);
    vals[j] = v;
    s  += v[0] + v[1] + v[2] + v[3];
    s2 += v[0]*v[0] + v[1]*v[1] + v[2]*v[2] + v[3]*v[3];
  }
  #pragma unroll
  for (int o = 32; o; o >>= 1) { s += __shfl_xor(s, o); s2 += __shfl_xor(s2, o); }
  if ((t & 63) == 0) { rs[sub][t >> 6][0] = s; rs[sub][t >> 6][1] = s2; }
  __syncthreads();
  s  = rs[sub][0][0] + rs[sub][1][0] + rs[sub][2][0] + rs[sub][3][0];
  s2 = rs[sub][0][1] + rs[sub][1][1] + rs[sub][2][1] + rs[sub][3][1];
  const float mean = s * (1.f / 4096.f);
  const float var  = s2 * (1.f / 4096.f) - mean * mean;
  const float rstd = rsqrtf(var + 1e-5f);
  #pragma unroll
  for (int j = 0; j < 4; ++j) {
    const int cl = j * 4 + (t >> 6);
    const int c = g * 16 + cl;
    const float sc = gw[c] * rstd;
    const float sh = gb[c] - mean * sc;
    f32x4 v = vals[j];
    us4 o;
    #pragma unroll
    for (int q = 0; q < 4; ++q) o[q] = f2bf(v[q] * sc + sh);
    *(us4*)&tile[sub * 16 + cl][(t & 63) * 4] = o;
  }
  __syncthreads();
  const int srow = tid >> 1, half = tid & 1;
  us8 o0, o1;
  #pragma unroll
  for (int c = 0; c < 8; ++c) o0[c] = tile[half * 16 + c][srow];
  #pragma unroll
  for (int c = 0; c < 8; ++c) o1[c] = tile[half * 16 + 8 + c][srow];
  unsigned short* dst = hT + ((size_t)b * 256 + srow) * 512 + gp * 32 + half * 16;
  *(us8*)dst = o0;
  *(us8*)(dst + 8) = o1;
}

// ---- pipelined B^T-form GEMM: C[bz][m][n] = sum_k A[m][k]*B[n][k] (+bias)(+resid)
// SWZ=1: 1D grid 2048; all 8 blocks (4m x 2n) of a batch bound to one XCD
// (xcd = L&7 round-robin), so the shared per-batch panel stays in that XCD's L2.
template<int BM, int BN, int MI, int TPB, int NWN, int NTT,
         int BIAS_MODE, bool OUT_F32, bool HAS_RESID, bool NFAST, int SWZ = 0>
__global__ __launch_bounds__(TPB, 2) void gemmp_k(
    const unsigned short* __restrict__ A, long long sAb, int lda,
    const unsigned short* __restrict__ B, long long sBb, int ldb,
    void* __restrict__ Cv, long long sCb, int ldc,
    const float* __restrict__ bias, const float* __restrict__ resid)
{
  constexpr int CA = BM * 8 / TPB;
  constexpr int CB = BN * 8 / TPB;
  __shared__ unsigned short SMEM[2 * BM * 64 + 2 * BN * 64];
  unsigned short* AsBase = SMEM;
  unsigned short* BsBase = SMEM + 2 * BM * 64;
  const int tid = threadIdx.x;
  int bz, bm, bn;
  if (SWZ) {
    const int L = blockIdx.x;
    const int xcd = L & 7, j = (L >> 3) & 7, bhi = L >> 6;
    bz = bhi * 8 + xcd;
    bm = (j >> 1) * BM;
    bn = (j & 1) * BN;
  } else {
    bz = blockIdx.z;
    bm = (NFAST ? blockIdx.y : blockIdx.x) * BM;
    bn = (NFAST ? blockIdx.x : blockIdx.y) * BN;
  }
  const int lane = tid & 63, w = tid >> 6;
  const int wr = w / NWN, wc = w % NWN;
  const int lr = lane & 15, lg = lane >> 4;
  const int csw = lr & 7;
  const int ko0 = (lg ^ csw) * 8;
  const int ko1 = ((4 + lg) ^ csw) * 8;

  const unsigned short* aSrc[CA]; int aOff[CA];
  #pragma unroll
  for (int p = 0; p < CA; ++p) {
    const int id = p * TPB + tid;
    const int row = id >> 3, cc = (id & 7) ^ (row & 7);
    aSrc[p] = A + (size_t)bz * sAb + (size_t)(bm + row) * lda + cc * 8;
    aOff[p] = id * 8;
  }
  const unsigned short* bSrc[CB]; int bOff[CB];
  #pragma unroll
  for (int p = 0; p < CB; ++p) {
    const int id = p * TPB + tid;
    const int row = id >> 3, cc = (id & 7) ^ (row & 7);
    bSrc[p] = B + (size_t)bz * sBb + (size_t)(bn + row) * ldb + cc * 8;
    bOff[p] = id * 8;
  }

  f32x4 acc[MI][4];
  #pragma unroll
  for (int i = 0; i < MI; ++i)
    #pragma unroll
    for (int j = 0; j < 4; ++j) acc[i][j] = (f32x4){0.f, 0.f, 0.f, 0.f};

  #pragma unroll
  for (int p = 0; p < CA; ++p) gll16(aSrc[p], &AsBase[aOff[p]]);
  #pragma unroll
  for (int p = 0; p < CB; ++p) gll16(bSrc[p], &BsBase[bOff[p]]);
  asm volatile("s_waitcnt vmcnt(0)" ::: "memory");
  __builtin_amdgcn_s_barrier();

  #pragma unroll 2
  for (int t = 0; t < NTT; ++t) {
    if (t + 1 < NTT) {
      const int k1 = (t + 1) * 64, sl = (t + 1) & 1;
      #pragma unroll
      for (int p = 0; p < CA; ++p) gll16(aSrc[p] + k1, &AsBase[sl * BM * 64 + aOff[p]]);
      #pragma unroll
      for (int p = 0; p < CB; ++p) gll16(bSrc[p] + k1, &BsBase[sl * BN * 64 + bOff[p]]);
    }
    const unsigned short* At = &AsBase[(t & 1) * BM * 64];
    const unsigned short* Bt = &BsBase[(t & 1) * BN * 64];
    short8 bf[4][2];
    #pragma unroll
    for (int nj = 0; nj < 4; ++nj) {
      bf[nj][0] = *(const short8*)(Bt + (wc * 64 + nj * 16 + lr) * 64 + ko0);
      bf[nj][1] = *(const short8*)(Bt + (wc * 64 + nj * 16 + lr) * 64 + ko1);
    }
    #pragma unroll
    for (int h = 0; h < MI / 4; ++h) {
      short8 af[4][2];
      #pragma unroll
      for (int mi = 0; mi < 4; ++mi) {
        const int rr = wr * (MI * 16) + h * 64 + mi * 16 + lr;
        af[mi][0] = *(const short8*)(At + rr * 64 + ko0);
        af[mi][1] = *(const short8*)(At + rr * 64 + ko1);
      }
      __builtin_amdgcn_s_setprio(1);
      #pragma unroll
      for (int mi = 0; mi < 4; ++mi)
        #pragma unroll
        for (int nj = 0; nj < 4; ++nj) {
          acc[h * 4 + mi][nj] = __builtin_amdgcn_mfma_f32_16x16x32_bf16(af[mi][0], bf[nj][0], acc[h * 4 + mi][nj], 0, 0, 0);
          acc[h * 4 + mi][nj] = __builtin_amdgcn_mfma_f32_16x16x32_bf16(af[mi][1], bf[nj][1], acc[h * 4 + mi][nj], 0, 0, 0);
        }
      __builtin_amdgcn_s_setprio(0);
    }
    if (t + 1 < NTT) {
      asm volatile("s_waitcnt vmcnt(0)" ::: "memory");
      __builtin_amdgcn_s_barrier();
    }
  }

  #pragma unroll
  for (int mi = 0; mi < MI; ++mi) {
    #pragma unroll
    for (int r = 0; r < 4; ++r) {
      const int rowc = bm + wr * (MI * 16) + mi * 16 + lg * 4 + r;
      const float bv_ = (BIAS_MODE == 1) ? bias[rowc] : 0.f;
      #pragma unroll
      for (int ni = 0; ni < 4; ++ni) {
        const int col = bn + wc * 64 + ni * 16 + lr;
        float vv = acc[mi][ni][r] + bv_;
        if (BIAS_MODE == 2) vv += bias[col];
        const size_t idx = (size_t)bz * sCb + (size_t)rowc * ldc + col;
        if (HAS_RESID) vv += resid[idx];
        if (OUT_F32) ((float*)Cv)[idx] = vv;
        else ((unsigned short*)Cv)[idx] = f2bf(vv);
      }
    }
  }
}

// ---- FUSED G2+G3: per batch, att = softmax(T1' hT^T / sqrt(512)) kept in LDS,
// then oT[b][t][c] = att x v[b]^T. QK phase = proven gemm3 structure.
__global__ __launch_bounds__(512, 1) void fused_k(
    const unsigned short* __restrict__ A,   // T1' [b][256][512]
    const unsigned short* __restrict__ B,   // hT  [b][256][512]
    const unsigned short* __restrict__ V,   // v   [b][512][256]
    unsigned short* __restrict__ O)         // oT  [b][256][512]
{
  __shared__ __attribute__((aligned(16))) char SM[147456];   // 144 KB
  unsigned short* AsB = (unsigned short*)SM;                 // QK: 4 slots x 16KB
  unsigned short* BsB = (unsigned short*)(SM + 65536);       // QK: 4 slots x 16KB
  unsigned short* attL = (unsigned short*)SM;                // PV: [256][256] swizzled (aliases QK bufs)
  unsigned short* vbuf = (unsigned short*)(SM + 131072);     // PV: [128][64]
  float* redm = (float*)(SM + 131072);                       // softmax scratch (dead before vbuf use)
  float* reds = redm + 1024;

  const int tid = threadIdx.x;
  const int bz = blockIdx.z;
  const int lane = tid & 63, w = tid >> 6;
  const int wr = w >> 2, wc = w & 3;
  const int lr = lane & 15, lg = lane >> 4;
  const int csw = lr & 7;
  const int ko0 = (lg ^ csw) * 8;
  const int ko1 = ((4 + lg) ^ csw) * 8;

  const int rl = tid >> 3;
  const int gc = (tid & 7) ^ (rl & 7);
  const unsigned short* pA = A + (size_t)bz * 131072 + (size_t)rl * 512 + gc * 8;
  const unsigned short* pB = B + (size_t)bz * 131072 + (size_t)rl * 512 + gc * 8;

  auto stageA = [&](int t, int h) {
    const unsigned short* s = pA + (size_t)h * 65536 + t * 64;
    unsigned short* d = AsB + ((2 * t + h) & 3) * 8192 + tid * 8;
    gll16(s, d);
    gll16(s + 32768, d + 4096);
  };
  auto stageB = [&](int t, int h) {
    const unsigned short* s = pB + (size_t)h * 65536 + t * 64;
    unsigned short* d = BsB + ((2 * t + h) & 3) * 8192 + tid * 8;
    gll16(s, d);
    gll16(s + 32768, d + 4096);
  };

  f32x4 acc[8][4];
  #pragma unroll
  for (int i = 0; i < 8; ++i)
    #pragma unroll
    for (int j = 0; j < 4; ++j) acc[i][j] = (f32x4){0.f, 0.f, 0.f, 0.f};

  stageA(0, 0); stageA(0, 1); stageB(0, 0); stageB(0, 1);
  stageB(1, 0); stageA(1, 0); stageA(1, 1);
  asm volatile("s_waitcnt vmcnt(6)" ::: "memory");
  __builtin_amdgcn_s_barrier();

  constexpr int NT = 8;
  for (int t = 0; t < NT; ++t) {
    const unsigned short* sA = AsB + ((2 * t + wr) & 3) * 8192;
    const unsigned short* sB = BsB + ((2 * t + (wc >> 1)) & 3) * 8192;
    const int bc = (wc & 1) * 64;
    short8 af[4][2], bf0[2][2], bf1[2][2];

    #pragma unroll
    for (int mi = 0; mi < 4; ++mi) {
      af[mi][0] = *(const short8*)(sA + (mi * 16 + lr) * 64 + ko0);
      af[mi][1] = *(const short8*)(sA + (mi * 16 + lr) * 64 + ko1);
    }
    #pragma unroll
    for (int nj = 0; nj < 2; ++nj) {
      bf0[nj][0] = *(const short8*)(sB + (bc + nj * 16 + lr) * 64 + ko0);
      bf0[nj][1] = *(const short8*)(sB + (bc + nj * 16 + lr) * 64 + ko1);
    }
    if (t + 1 < NT) stageB(t + 1, 1);
    __builtin_amdgcn_s_barrier();
    __builtin_amdgcn_s_setprio(1);
    #pragma unroll
    for (int mi = 0; mi < 4; ++mi)
      #pragma unroll
      for (int nj = 0; nj < 2; ++nj) {
        acc[mi][nj] = __builtin_amdgcn_mfma_f32_16x16x32_bf16(af[mi][0], bf0[nj][0], acc[mi][nj], 0, 0, 0);
        acc[mi][nj] = __builtin_amdgcn_mfma_f32_16x16x32_bf16(af[mi][1], bf0[nj][1], acc[mi][nj], 0, 0, 0);
      }
    __builtin_amdgcn_s_setprio(0);
    __builtin_amdgcn_s_barrier();

    #pragma unroll
    for (int nj = 0; nj < 2; ++nj) {
      bf1[nj][0] = *(const short8*)(sB + (bc + 32 + nj * 16 + lr) * 64 + ko0);
      bf1[nj][1] = *(const short8*)(sB + (bc + 32 + nj * 16 + lr) * 64 + ko1);
    }
    __builtin_amdgcn_s_barrier();
    __builtin_amdgcn_s_setprio(1);
    #pragma unroll
    for (int mi = 0; mi < 4; ++mi)
      #pragma unroll
      for (int nj = 0; nj < 2; ++nj) {
        acc[mi][2 + nj] = __builtin_amdgcn_mfma_f32_16x16x32_bf16(af[mi][0], bf1[nj][0], acc[mi][2 + nj], 0, 0, 0);
        acc[mi][2 + nj] = __builtin_amdgcn_mfma_f32_16x16x32_bf16(af[mi][1], bf1[nj][1], acc[mi][2 + nj], 0, 0, 0);
      }
    __builtin_amdgcn_s_setprio(0);
    __builtin_amdgcn_s_barrier();

    #pragma unroll
    for (int mi = 0; mi < 4; ++mi) {
      af[mi][0] = *(const short8*)(sA + (64 + mi * 16 + lr) * 64 + ko0);
      af[mi][1] = *(const short8*)(sA + (64 + mi * 16 + lr) * 64 + ko1);
    }
    if (t + 2 < NT) stageB(t + 2, 0);
    __builtin_amdgcn_s_barrier();
    __builtin_amdgcn_s_setprio(1);
    #pragma unroll
    for (int mi = 0; mi < 4; ++mi)
      #pragma unroll
      for (int nj = 0; nj < 2; ++nj) {
        acc[4 + mi][nj] = __builtin_amdgcn_mfma_f32_16x16x32_bf16(af[mi][0], bf0[nj][0], acc[4 + mi][nj], 0, 0, 0);
        acc[4 + mi][nj] = __builtin_amdgcn_mfma_f32_16x16x32_bf16(af[mi][1], bf0[nj][1], acc[4 + mi][nj], 0, 0, 0);
      }
    __builtin_amdgcn_s_setprio(0);
    __builtin_amdgcn_s_barrier();

    if (t + 2 < NT) { stageA(t + 2, 0); stageA(t + 2, 1); }
    __builtin_amdgcn_s_barrier();
    __builtin_amdgcn_s_setprio(1);
    #pragma unroll
    for (int mi = 0; mi < 4; ++mi)
      #pragma unroll
      for (int nj = 0; nj < 2; ++nj) {
        acc[4 + mi][2 + nj] = __builtin_amdgcn_mfma_f32_16x16x32_bf16(af[mi][0], bf1[nj][0], acc[4 + mi][2 + nj], 0, 0, 0);
        acc[4 + mi][2 + nj] = __builtin_amdgcn_mfma_f32_16x16x32_bf16(af[mi][1], bf1[nj][1], acc[4 + mi][2 + nj], 0, 0, 0);
      }
    __builtin_amdgcn_s_setprio(0);
    if (t == NT - 2)      asm volatile("s_waitcnt vmcnt(0)" ::: "memory");
    else if (t < NT - 2)  asm volatile("s_waitcnt vmcnt(6)" ::: "memory");
    __builtin_amdgcn_s_barrier();
  }

  // ---- softmax (reductions in SM+131072 scratch)
  const float SC = 0.044194173824159216f;
  float rmax[8][4];
  #pragma unroll
  for (int mi = 0; mi < 8; ++mi)
    #pragma unroll
    for (int r = 0; r < 4; ++r) {
      float m = fmaxf(fmaxf(acc[mi][0][r], acc[mi][1][r]),
                      fmaxf(acc[mi][2][r], acc[mi][3][r]));
      #pragma unroll
      for (int o = 1; o <= 8; o <<= 1) m = fmaxf(m, __shfl_xor(m, o));
      rmax[mi][r] = m;
    }
  __syncthreads();
  if (lr == 0) {
    #pragma unroll
    for (int mi = 0; mi < 8; ++mi)
      #pragma unroll
      for (int r = 0; r < 4; ++r)
        redm[(wr * 128 + mi * 16 + lg * 4 + r) * 4 + wc] = rmax[mi][r];
  }
  __syncthreads();
  float rsum[8][4];
  #pragma unroll
  for (int mi = 0; mi < 8; ++mi)
    #pragma unroll
    for (int r = 0; r < 4; ++r) {
      const int row = wr * 128 + mi * 16 + lg * 4 + r;
      f32x4 q = *(const f32x4*)&redm[row * 4];
      const float m = fmaxf(fmaxf(q[0], q[1]), fmaxf(q[2], q[3]));
      float s = 0.f;
      #pragma unroll
      for (int ni = 0; ni < 4; ++ni) {
        float e = __expf((acc[mi][ni][r] - m) * SC);
        acc[mi][ni][r] = e;
        s += e;
      }
      #pragma unroll
      for (int o = 1; o <= 8; o <<= 1) s += __shfl_xor(s, o);
      rsum[mi][r] = s;
    }
  if (lr == 0) {
    #pragma unroll
    for (int mi = 0; mi < 8; ++mi)
      #pragma unroll
      for (int r = 0; r < 4; ++r)
        reds[(wr * 128 + mi * 16 + lg * 4 + r) * 4 + wc] = rsum[mi][r];
  }
  __syncthreads();

  // ---- write probabilities to attL [256 t][256 s] (XOR-chunk A-fragment layout)
  #pragma unroll
  for (int mi = 0; mi < 8; ++mi)
    #pragma unroll
    for (int r = 0; r < 4; ++r) {
      const int trow = wr * 128 + mi * 16 + lg * 4 + r;
      f32x4 q = *(const f32x4*)&reds[trow * 4];
      const float inv = 1.f / (q[0] + q[1] + q[2] + q[3]);
      const int t7 = trow & 7;
      #pragma unroll
      for (int ni = 0; ni < 4; ++ni) {
        const int cw = ni * 2 + (lr >> 3);            // chunk within 64-window
        const int off = trow * 256 + wc * 64 + ((cw ^ t7) << 3) + (lr & 7);
        attL[off] = f2bf(acc[mi][ni][r] * inv);
      }
    }
  __syncthreads();

  // ---- PV: oT[t][c] = sum_s att[t][s] v[c][s]; 4 col-passes x 4 K-steps
  const unsigned short* Vb = V + (size_t)bz * 131072;
  unsigned short* Ob = O + (size_t)bz * 131072;
  const int vrow = tid >> 3;                           // stage: [128 c][64 s]
  const int vgc = (tid & 7) ^ (vrow & 7);
  for (int pass = 0; pass < 4; ++pass) {
    f32x4 po[8][2];
    #pragma unroll
    for (int i = 0; i < 8; ++i)
      #pragma unroll
      for (int j = 0; j < 2; ++j) po[i][j] = (f32x4){0.f, 0.f, 0.f, 0.f};
    for (int kt = 0; kt < 4; ++kt) {
      #pragma unroll
      for (int p = 0; p < 2; ++p) {
        const int id = p * 512 + tid;
        const int rowv = p * 64 + vrow;
        gll16(Vb + (size_t)(pass * 128 + rowv) * 256 + kt * 64 + vgc * 8,
              vbuf + id * 8);
      }
      asm volatile("s_waitcnt vmcnt(0)" ::: "memory");
      __builtin_amdgcn_s_barrier();
      short8 bfv[2][2];
      #pragma unroll
      for (int nj = 0; nj < 2; ++nj) {
        bfv[nj][0] = *(const short8*)(vbuf + (wc * 32 + nj * 16 + lr) * 64 + ko0);
        bfv[nj][1] = *(const short8*)(vbuf + (wc * 32 + nj * 16 + lr) * 64 + ko1);
      }
      __builtin_amdgcn_s_setprio(1);
      #pragma unroll
      for (int mi = 0; mi < 8; ++mi) {
        const int trow = wr * 128 + mi * 16 + lr;
        const int t7 = trow & 7;
        const unsigned short* ap = attL + trow * 256 + kt * 64;
        short8 afv0 = *(const short8*)(ap + ((lg ^ t7) << 3));
        short8 afv1 = *(const short8*)(ap + (((4 + lg) ^ t7) << 3));
        #pragma unroll
        for (int nj = 0; nj < 2; ++nj) {
          po[mi][nj] = __builtin_amdgcn_mfma_f32_16x16x32_bf16(afv0, bfv[nj][0], po[mi][nj], 0, 0, 0);
          po[mi][nj] = __builtin_amdgcn_mfma_f32_16x16x32_bf16(afv1, bfv[nj][1], po[mi][nj], 0, 0, 0);
        }
      }
      __builtin_amdgcn_s_setprio(0);
      __builtin_amdgcn_s_barrier();
    }
    #pragma unroll
    for (int mi = 0; mi < 8; ++mi)
      #pragma unroll
      for (int r = 0; r < 4; ++r) {
        const int trow = wr * 128 + mi * 16 + lg * 4 + r;
        #pragma unroll
        for (int nj = 0; nj < 2; ++nj) {
          const int c = pass * 128 + wc * 32 + nj * 16 + lr;
          Ob[(size_t)trow * 512 + c] = f2bf(po[mi][nj][r]);
        }
      }
  }
}

extern "C" void kernel_launch(void* const* d_in, const int* in_sizes, int n_in,
                              void* d_out, int out_size, void* d_ws, size_t ws_size,
                              hipStream_t stream)
{
  const float* x   = (const float*)d_in[0];
  const float* gnw = (const float*)d_in[1];
  const float* gnb = (const float*)d_in[2];
  const float* wq  = (const float*)d_in[3];
  const float* bq  = (const float*)d_in[4];
  const float* wk  = (const float*)d_in[5];
  // bk cancels in softmax
  const float* wv  = (const float*)d_in[7];
  const float* bv  = (const float*)d_in[8];
  const float* wp  = (const float*)d_in[9];
  const float* bp  = (const float*)d_in[10];
  float* out = (float*)d_out;

  char* ws = (char*)d_ws;
  unsigned short* W2T   = (unsigned short*)(ws);                  // [512][512] bf16
  unsigned short* wvb   = (unsigned short*)(ws + 524288);
  unsigned short* wpb   = (unsigned short*)(ws + 1048576);
  unsigned short* wqT   = (unsigned short*)(ws + 1572864);
  unsigned short* wkT   = (unsigned short*)(ws + 2097152);
  float*          w2b   = (float*)(ws + 2621440);
  unsigned short* hT    = (unsigned short*)(ws + 2885632);        // 65536x512 bf16 (reused as oT)
  unsigned short* T1    = (unsigned short*)(ws + 69994496ull);    // 65536x512 bf16
  unsigned short* v     = (unsigned short*)(ws + 137103360ull);   // B*512*256 bf16
  unsigned short* oT    = hT;

  conv_k<<<512, 256, 0, stream>>>(wv, wp, wvb, wpb);
  tk<<<dim3(8, 8, 2), 256, 0, stream>>>(wq, wk, wqT, wkT);
  w2b_k<<<8, 256, 0, stream>>>(wkT, bq, w2b);
  // W2T[d][c] = sum_o wk[o][d]*wq[o][c]
  gemmp_k<128, 128, 4, 256, 2, 8, 0, false, false, false><<<dim3(4, 4, 1), 256, 0, stream>>>(
      wkT, 0, 512, wqT, 0, 512, W2T, 0, 512, nullptr, nullptr);
  gn_k<<<4096, 512, 0, stream>>>(x, gnw, gnb, hT);
  // G1 (flat): T1'[s][d] = hT x W2T^T + w2b[d]
  gemmp_k<256, 256, 8, 512, 4, 8, 2, false, false, true><<<dim3(2, 256, 1), 512, 0, stream>>>(
      hT, 0, 512, W2T, 0, 512, T1, 0, 512, w2b, nullptr);
  // G1b (per-batch, XCD-swizzled): v[b][c][s] = wvb x hT[b]^T + bv
  gemmp_k<128, 128, 4, 256, 2, 8, 1, false, false, false, 1><<<dim3(2048, 1, 1), 256, 0, stream>>>(
      wvb, 0, 512, hT, 131072, 512, v, 131072, 256, bv, nullptr);
  // FUSED G2+G3: att in LDS, oT[b] = softmax(T1' hT^T) x v^T
  fused_k<<<dim3(1, 1, 256), 512, 0, stream>>>(T1, hT, v, oT);
  // G4 (per-batch, XCD-swizzled): out[b][c][s] = wpb x oT[b]^T + bp + x
  gemmp_k<128, 128, 4, 256, 2, 8, 1, true, true, false, 1><<<dim3(2048, 1, 1), 256, 0, stream>>>(
      wpb, 0, 512, oT, 131072, 512, out, 131072, 256, bp, x);
}

// Round 13
// 300.464 us; speedup vs baseline: 1.3752x; 1.0001x over previous
//
#include <hip/hip_runtime.h>

typedef __attribute__((ext_vector_type(8))) short short8;
typedef __attribute__((ext_vector_type(8))) unsigned short us8;
typedef __attribute__((ext_vector_type(4))) unsigned short us4;
typedef __attribute__((ext_vector_type(4))) float f32x4;

static __device__ __forceinline__ unsigned short f2bf(float f) {
  union { float f; unsigned u; } c; c.f = f;
  unsigned r = (c.u + 0x7FFFu + ((c.u >> 16) & 1u)) >> 16;
  return (unsigned short)r;
}
static __device__ __forceinline__ float b2f(unsigned short h) {
  union { unsigned u; float f; } c; c.u = ((unsigned)h) << 16; return c.f;
}

static __device__ __forceinline__ void gll16(const unsigned short* g, unsigned short* l) {
  __builtin_amdgcn_global_load_lds(
      (const __attribute__((address_space(1))) unsigned int*)g,
      (__attribute__((address_space(3))) unsigned int*)l, 16, 0, 0);
}

// ---- wv, wp -> bf16
__global__ __launch_bounds__(256) void conv_k(
    const float* __restrict__ wv, const float* __restrict__ wp,
    unsigned short* __restrict__ wvb, unsigned short* __restrict__ wpb)
{
  int i4 = (blockIdx.x * 256 + threadIdx.x) * 4;
  const float* src;
  unsigned short* dst;
  if (i4 < 262144) { src = wv + i4; dst = wvb + i4; }
  else             { src = wp + (i4 - 262144); dst = wpb + (i4 - 262144); }
  f32x4 v = *(const f32x4*)src;
  us4 o;
  #pragma unroll
  for (int j = 0; j < 4; ++j) o[j] = f2bf(v[j]);
  *(us4*)dst = o;
}

// ---- transpose wq,wk (f32 [512][512]) -> wqT,wkT (bf16 [c][o])
__global__ __launch_bounds__(256) void tk(
    const float* __restrict__ wq, const float* __restrict__ wk,
    unsigned short* __restrict__ wqT, unsigned short* __restrict__ wkT)
{
  __shared__ float L[64][65];
  const float* src = blockIdx.z ? wk : wq;
  unsigned short* dst = blockIdx.z ? wkT : wqT;
  const int ro = blockIdx.x * 64, co = blockIdx.y * 64;
  const int tid = threadIdx.x;
  #pragma unroll
  for (int p = 0; p < 4; ++p) {
    int lin = p * 1024 + tid * 4;
    int r = lin >> 6, cl = lin & 63;
    *(f32x4*)&L[r][cl] = *(const f32x4*)(src + (size_t)(ro + r) * 512 + co + cl);
  }
  __syncthreads();
  #pragma unroll
  for (int p = 0; p < 4; ++p) {
    int lin = p * 1024 + tid * 4;
    int rr = lin >> 6, cc = lin & 63;
    us4 o;
    #pragma unroll
    for (int j = 0; j < 4; ++j) o[j] = f2bf(L[cc + j][rr]);
    *(us4*)(dst + (size_t)(co + rr) * 512 + ro + cc) = o;
  }
}

// ---- w2b[c] = sum_o bq[o] * wk[o][c]
__global__ __launch_bounds__(256) void w2b_k(
    const unsigned short* __restrict__ wkT, const float* __restrict__ bq,
    float* __restrict__ w2b)
{
  const int wv_ = threadIdx.x >> 6, lane = threadIdx.x & 63;
  for (int i = 0; i < 16; ++i) {
    const int c = blockIdx.x * 64 + i * 4 + wv_;
    us8 kv = *(const us8*)(wkT + (size_t)c * 512 + lane * 8);
    float s = 0.f;
    #pragma unroll
    for (int j = 0; j < 8; ++j) s += b2f(kv[j]) * bq[lane * 8 + j];
    #pragma unroll
    for (int o = 32; o; o >>= 1) s += __shfl_xor(s, o);
    if (lane == 0) w2b[c] = s;
  }
}

// ---- GroupNorm -> hT [b][s=256][c=512] bf16
__global__ __launch_bounds__(512) void gn_k(
    const float* __restrict__ x, const float* __restrict__ gw,
    const float* __restrict__ gb, unsigned short* __restrict__ hT)
{
  __shared__ unsigned short tile[32][256];
  __shared__ float rs[2][4][2];
  const int b = blockIdx.x >> 4, gp = blockIdx.x & 15;
  const int tid = threadIdx.x;
  const int sub = tid >> 8;
  const int t = tid & 255;
  const int g = gp * 2 + sub;
  const float* xp = x + ((size_t)b * 512 + g * 16) * 256;
  f32x4 vals[4];
  float s = 0.f, s2 = 0.f;
  #pragma unroll
  for (int j = 0; j < 4; ++j) {
    f32x4 v = *(const f32x4*)(xp + j * 1024 + t * 4);
    vals[j] = v;
    s  += v[0] + v[1] + v[2] + v[3];
    s2 += v[0]*v[0] + v[1]*v[1] + v[2]*v[2] + v[3]*v[3];
  }
  #pragma unroll
  for (int o = 32; o; o >>= 1) { s += __shfl_xor(s, o); s2 += __shfl_xor(s2, o); }
  if ((t & 63) == 0) { rs[sub][t >> 6][0] = s; rs[sub][t >> 6][1] = s2; }
  __syncthreads();
  s  = rs[sub][0][0] + rs[sub][1][0] + rs[sub][2][0] + rs[sub][3][0];
  s2 = rs[sub][0][1] + rs[sub][1][1] + rs[sub][2][1] + rs[sub][3][1];
  const float mean = s * (1.f / 4096.f);
  const float var  = s2 * (1.f / 4096.f) - mean * mean;
  const float rstd = rsqrtf(var + 1e-5f);
  #pragma unroll
  for (int j = 0; j < 4; ++j) {
    const int cl = j * 4 + (t >> 6);
    const int c = g * 16 + cl;
    const float sc = gw[c] * rstd;
    const float sh = gb[c] - mean * sc;
    f32x4 v = vals[j];
    us4 o;
    #pragma unroll
    for (int q = 0; q < 4; ++q) o[q] = f2bf(v[q] * sc + sh);
    *(us4*)&tile[sub * 16 + cl][(t & 63) * 4] = o;
  }
  __syncthreads();
  const int srow = tid >> 1, half = tid & 1;
  us8 o0, o1;
  #pragma unroll
  for (int c = 0; c < 8; ++c) o0[c] = tile[half * 16 + c][srow];
  #pragma unroll
  for (int c = 0; c < 8; ++c) o1[c] = tile[half * 16 + 8 + c][srow];
  unsigned short* dst = hT + ((size_t)b * 256 + srow) * 512 + gp * 32 + half * 16;
  *(us8*)dst = o0;
  *(us8*)(dst + 8) = o1;
}

// ---- pipelined B^T-form GEMM: C[bz][m][n] = sum_k A[m][k]*B[n][k] (+bias)(+resid)
// SWZ=1: 1D grid 2048; all 8 blocks of a batch bound to one XCD (L&7).
// SBA=1: single-buffered A tile (A = L2-hot weight) -> LDS 48KB, 3 blocks/CU.
template<int BM, int BN, int MI, int TPB, int NWN, int NTT,
         int BIAS_MODE, bool OUT_F32, bool HAS_RESID, bool NFAST,
         int SWZ = 0, bool SBA = false, int MINW = 2>
__global__ __launch_bounds__(TPB, MINW) void gemmp_k(
    const unsigned short* __restrict__ A, long long sAb, int lda,
    const unsigned short* __restrict__ B, long long sBb, int ldb,
    void* __restrict__ Cv, long long sCb, int ldc,
    const float* __restrict__ bias, const float* __restrict__ resid)
{
  constexpr int CA = BM * 8 / TPB;
  constexpr int CB = BN * 8 / TPB;
  constexpr int ASL = SBA ? BM * 64 : 2 * BM * 64;
  __shared__ unsigned short SMEM[ASL + 2 * BN * 64];
  unsigned short* AsBase = SMEM;
  unsigned short* BsBase = SMEM + ASL;
  const int tid = threadIdx.x;
  int bz, bm, bn;
  if (SWZ) {
    const int L = blockIdx.x;
    const int xcd = L & 7, j = (L >> 3) & 7, bhi = L >> 6;
    bz = bhi * 8 + xcd;
    bm = (j >> 1) * BM;
    bn = (j & 1) * BN;
  } else {
    bz = blockIdx.z;
    bm = (NFAST ? blockIdx.y : blockIdx.x) * BM;
    bn = (NFAST ? blockIdx.x : blockIdx.y) * BN;
  }
  const int lane = tid & 63, w = tid >> 6;
  const int wr = w / NWN, wc = w % NWN;
  const int lr = lane & 15, lg = lane >> 4;
  const int csw = lr & 7;
  const int ko0 = (lg ^ csw) * 8;
  const int ko1 = ((4 + lg) ^ csw) * 8;

  const unsigned short* aSrc[CA]; int aOff[CA];
  #pragma unroll
  for (int p = 0; p < CA; ++p) {
    const int id = p * TPB + tid;
    const int row = id >> 3, cc = (id & 7) ^ (row & 7);
    aSrc[p] = A + (size_t)bz * sAb + (size_t)(bm + row) * lda + cc * 8;
    aOff[p] = id * 8;
  }
  const unsigned short* bSrc[CB]; int bOff[CB];
  #pragma unroll
  for (int p = 0; p < CB; ++p) {
    const int id = p * TPB + tid;
    const int row = id >> 3, cc = (id & 7) ^ (row & 7);
    bSrc[p] = B + (size_t)bz * sBb + (size_t)(bn + row) * ldb + cc * 8;
    bOff[p] = id * 8;
  }

  f32x4 acc[MI][4];
  #pragma unroll
  for (int i = 0; i < MI; ++i)
    #pragma unroll
    for (int j = 0; j < 4; ++j) acc[i][j] = (f32x4){0.f, 0.f, 0.f, 0.f};

  #pragma unroll
  for (int p = 0; p < CA; ++p) gll16(aSrc[p], &AsBase[aOff[p]]);
  #pragma unroll
  for (int p = 0; p < CB; ++p) gll16(bSrc[p], &BsBase[bOff[p]]);
  asm volatile("s_waitcnt vmcnt(0)" ::: "memory");
  __builtin_amdgcn_s_barrier();

  #pragma unroll 2
  for (int t = 0; t < NTT; ++t) {
    if (t + 1 < NTT) {
      const int k1 = (t + 1) * 64, sl = (t + 1) & 1;
      if (!SBA) {
        #pragma unroll
        for (int p = 0; p < CA; ++p) gll16(aSrc[p] + k1, &AsBase[sl * BM * 64 + aOff[p]]);
      }
      #pragma unroll
      for (int p = 0; p < CB; ++p) gll16(bSrc[p] + k1, &BsBase[sl * BN * 64 + bOff[p]]);
    }
    const unsigned short* At = SBA ? AsBase : &AsBase[(t & 1) * BM * 64];
    const unsigned short* Bt = &BsBase[(t & 1) * BN * 64];
    short8 bf[4][2];
    #pragma unroll
    for (int nj = 0; nj < 4; ++nj) {
      bf[nj][0] = *(const short8*)(Bt + (wc * 64 + nj * 16 + lr) * 64 + ko0);
      bf[nj][1] = *(const short8*)(Bt + (wc * 64 + nj * 16 + lr) * 64 + ko1);
    }
    #pragma unroll
    for (int h = 0; h < MI / 4; ++h) {
      short8 af[4][2];
      #pragma unroll
      for (int mi = 0; mi < 4; ++mi) {
        const int rr = wr * (MI * 16) + h * 64 + mi * 16 + lr;
        af[mi][0] = *(const short8*)(At + rr * 64 + ko0);
        af[mi][1] = *(const short8*)(At + rr * 64 + ko1);
      }
      __builtin_amdgcn_s_setprio(1);
      #pragma unroll
      for (int mi = 0; mi < 4; ++mi)
        #pragma unroll
        for (int nj = 0; nj < 4; ++nj) {
          acc[h * 4 + mi][nj] = __builtin_amdgcn_mfma_f32_16x16x32_bf16(af[mi][0], bf[nj][0], acc[h * 4 + mi][nj], 0, 0, 0);
          acc[h * 4 + mi][nj] = __builtin_amdgcn_mfma_f32_16x16x32_bf16(af[mi][1], bf[nj][1], acc[h * 4 + mi][nj], 0, 0, 0);
        }
      __builtin_amdgcn_s_setprio(0);
    }
    if (t + 1 < NTT) {
      asm volatile("s_waitcnt vmcnt(0)" ::: "memory");
      __builtin_amdgcn_s_barrier();
      if (SBA) {
        const int k1 = (t + 1) * 64;
        #pragma unroll
        for (int p = 0; p < CA; ++p) gll16(aSrc[p] + k1, &AsBase[aOff[p]]);
        asm volatile("s_waitcnt vmcnt(0)" ::: "memory");
        __builtin_amdgcn_s_barrier();
      }
    }
  }

  #pragma unroll
  for (int mi = 0; mi < MI; ++mi) {
    #pragma unroll
    for (int r = 0; r < 4; ++r) {
      const int rowc = bm + wr * (MI * 16) + mi * 16 + lg * 4 + r;
      const float bv_ = (BIAS_MODE == 1) ? bias[rowc] : 0.f;
      #pragma unroll
      for (int ni = 0; ni < 4; ++ni) {
        const int col = bn + wc * 64 + ni * 16 + lr;
        float vv = acc[mi][ni][r] + bv_;
        if (BIAS_MODE == 2) vv += bias[col];
        const size_t idx = (size_t)bz * sCb + (size_t)rowc * ldc + col;
        if (HAS_RESID) vv += resid[idx];
        if (OUT_F32) ((float*)Cv)[idx] = vv;
        else ((unsigned short*)Cv)[idx] = f2bf(vv);
      }
    }
  }
}

// ---- FUSED G2+G3: att = softmax(T1' hT^T / sqrt(512)) in LDS, then oT = att x v^T.
// PV v-slices use T14 async-STAGE (global->reg early, reg->LDS after barrier).
__global__ __launch_bounds__(512, 1) void fused_k(
    const unsigned short* __restrict__ A,   // T1' [b][256][512]
    const unsigned short* __restrict__ B,   // hT  [b][256][512]
    const unsigned short* __restrict__ V,   // v   [b][512][256]
    unsigned short* __restrict__ O)         // oT  [b][256][512]
{
  __shared__ __attribute__((aligned(16))) char SM[147456];   // 144 KB
  unsigned short* AsB = (unsigned short*)SM;                 // QK: 4 slots x 16KB
  unsigned short* BsB = (unsigned short*)(SM + 65536);       // QK: 4 slots x 16KB
  unsigned short* attL = (unsigned short*)SM;                // PV: [256][256] swizzled
  unsigned short* vbuf = (unsigned short*)(SM + 131072);     // PV: [128][64]
  float* redm = (float*)(SM + 131072);                       // softmax scratch
  float* reds = redm + 1024;

  const int tid = threadIdx.x;
  const int bz = blockIdx.z;
  const int lane = tid & 63, w = tid >> 6;
  const int wr = w >> 2, wc = w & 3;
  const int lr = lane & 15, lg = lane >> 4;
  const int csw = lr & 7;
  const int ko0 = (lg ^ csw) * 8;
  const int ko1 = ((4 + lg) ^ csw) * 8;

  const int rl = tid >> 3;
  const int gc = (tid & 7) ^ (rl & 7);
  const unsigned short* pA = A + (size_t)bz * 131072 + (size_t)rl * 512 + gc * 8;
  const unsigned short* pB = B + (size_t)bz * 131072 + (size_t)rl * 512 + gc * 8;

  auto stageA = [&](int t, int h) {
    const unsigned short* s = pA + (size_t)h * 65536 + t * 64;
    unsigned short* d = AsB + ((2 * t + h) & 3) * 8192 + tid * 8;
    gll16(s, d);
    gll16(s + 32768, d + 4096);
  };
  auto stageB = [&](int t, int h) {
    const unsigned short* s = pB + (size_t)h * 65536 + t * 64;
    unsigned short* d = BsB + ((2 * t + h) & 3) * 8192 + tid * 8;
    gll16(s, d);
    gll16(s + 32768, d + 4096);
  };

  f32x4 acc[8][4];
  #pragma unroll
  for (int i = 0; i < 8; ++i)
    #pragma unroll
    for (int j = 0; j < 4; ++j) acc[i][j] = (f32x4){0.f, 0.f, 0.f, 0.f};

  stageA(0, 0); stageA(0, 1); stageB(0, 0); stageB(0, 1);
  stageB(1, 0); stageA(1, 0); stageA(1, 1);
  asm volatile("s_waitcnt vmcnt(6)" ::: "memory");
  __builtin_amdgcn_s_barrier();

  constexpr int NT = 8;
  for (int t = 0; t < NT; ++t) {
    const unsigned short* sA = AsB + ((2 * t + wr) & 3) * 8192;
    const unsigned short* sB = BsB + ((2 * t + (wc >> 1)) & 3) * 8192;
    const int bc = (wc & 1) * 64;
    short8 af[4][2], bf0[2][2], bf1[2][2];

    #pragma unroll
    for (int mi = 0; mi < 4; ++mi) {
      af[mi][0] = *(const short8*)(sA + (mi * 16 + lr) * 64 + ko0);
      af[mi][1] = *(const short8*)(sA + (mi * 16 + lr) * 64 + ko1);
    }
    #pragma unroll
    for (int nj = 0; nj < 2; ++nj) {
      bf0[nj][0] = *(const short8*)(sB + (bc + nj * 16 + lr) * 64 + ko0);
      bf0[nj][1] = *(const short8*)(sB + (bc + nj * 16 + lr) * 64 + ko1);
    }
    if (t + 1 < NT) stageB(t + 1, 1);
    __builtin_amdgcn_s_barrier();
    __builtin_amdgcn_s_setprio(1);
    #pragma unroll
    for (int mi = 0; mi < 4; ++mi)
      #pragma unroll
      for (int nj = 0; nj < 2; ++nj) {
        acc[mi][nj] = __builtin_amdgcn_mfma_f32_16x16x32_bf16(af[mi][0], bf0[nj][0], acc[mi][nj], 0, 0, 0);
        acc[mi][nj] = __builtin_amdgcn_mfma_f32_16x16x32_bf16(af[mi][1], bf0[nj][1], acc[mi][nj], 0, 0, 0);
      }
    __builtin_amdgcn_s_setprio(0);
    __builtin_amdgcn_s_barrier();

    #pragma unroll
    for (int nj = 0; nj < 2; ++nj) {
      bf1[nj][0] = *(const short8*)(sB + (bc + 32 + nj * 16 + lr) * 64 + ko0);
      bf1[nj][1] = *(const short8*)(sB + (bc + 32 + nj * 16 + lr) * 64 + ko1);
    }
    __builtin_amdgcn_s_barrier();
    __builtin_amdgcn_s_setprio(1);
    #pragma unroll
    for (int mi = 0; mi < 4; ++mi)
      #pragma unroll
      for (int nj = 0; nj < 2; ++nj) {
        acc[mi][2 + nj] = __builtin_amdgcn_mfma_f32_16x16x32_bf16(af[mi][0], bf1[nj][0], acc[mi][2 + nj], 0, 0, 0);
        acc[mi][2 + nj] = __builtin_amdgcn_mfma_f32_16x16x32_bf16(af[mi][1], bf1[nj][1], acc[mi][2 + nj], 0, 0, 0);
      }
    __builtin_amdgcn_s_setprio(0);
    __builtin_amdgcn_s_barrier();

    #pragma unroll
    for (int mi = 0; mi < 4; ++mi) {
      af[mi][0] = *(const short8*)(sA + (64 + mi * 16 + lr) * 64 + ko0);
      af[mi][1] = *(const short8*)(sA + (64 + mi * 16 + lr) * 64 + ko1);
    }
    if (t + 2 < NT) stageB(t + 2, 0);
    __builtin_amdgcn_s_barrier();
    __builtin_amdgcn_s_setprio(1);
    #pragma unroll
    for (int mi = 0; mi < 4; ++mi)
      #pragma unroll
      for (int nj = 0; nj < 2; ++nj) {
        acc[4 + mi][nj] = __builtin_amdgcn_mfma_f32_16x16x32_bf16(af[mi][0], bf0[nj][0], acc[4 + mi][nj], 0, 0, 0);
        acc[4 + mi][nj] = __builtin_amdgcn_mfma_f32_16x16x32_bf16(af[mi][1], bf0[nj][1], acc[4 + mi][nj], 0, 0, 0);
      }
    __builtin_amdgcn_s_setprio(0);
    __builtin_amdgcn_s_barrier();

    if (t + 2 < NT) { stageA(t + 2, 0); stageA(t + 2, 1); }
    __builtin_amdgcn_s_barrier();
    __builtin_amdgcn_s_setprio(1);
    #pragma unroll
    for (int mi = 0; mi < 4; ++mi)
      #pragma unroll
      for (int nj = 0; nj < 2; ++nj) {
        acc[4 + mi][2 + nj] = __builtin_amdgcn_mfma_f32_16x16x32_bf16(af[mi][0], bf1[nj][0], acc[4 + mi][2 + nj], 0, 0, 0);
        acc[4 + mi][2 + nj] = __builtin_amdgcn_mfma_f32_16x16x32_bf16(af[mi][1], bf1[nj][1], acc[4 + mi][2 + nj], 0, 0, 0);
      }
    __builtin_amdgcn_s_setprio(0);
    if (t == NT - 2)      asm volatile("s_waitcnt vmcnt(0)" ::: "memory");
    else if (t < NT - 2)  asm volatile("s_waitcnt vmcnt(6)" ::: "memory");
    __builtin_amdgcn_s_barrier();
  }

  // ---- softmax
  const float SC = 0.044194173824159216f;
  float rmax[8][4];
  #pragma unroll
  for (int mi = 0; mi < 8; ++mi)
    #pragma unroll
    for (int r = 0; r < 4; ++r) {
      float m = fmaxf(fmaxf(acc[mi][0][r], acc[mi][1][r]),
                      fmaxf(acc[mi][2][r], acc[mi][3][r]));
      #pragma unroll
      for (int o = 1; o <= 8; o <<= 1) m = fmaxf(m, __shfl_xor(m, o));
      rmax[mi][r] = m;
    }
  __syncthreads();
  if (lr == 0) {
    #pragma unroll
    for (int mi = 0; mi < 8; ++mi)
      #pragma unroll
      for (int r = 0; r < 4; ++r)
        redm[(wr * 128 + mi * 16 + lg * 4 + r) * 4 + wc] = rmax[mi][r];
  }
  __syncthreads();
  float rsum[8][4];
  #pragma unroll
  for (int mi = 0; mi < 8; ++mi)
    #pragma unroll
    for (int r = 0; r < 4; ++r) {
      const int row = wr * 128 + mi * 16 + lg * 4 + r;
      f32x4 q = *(const f32x4*)&redm[row * 4];
      const float m = fmaxf(fmaxf(q[0], q[1]), fmaxf(q[2], q[3]));
      float s = 0.f;
      #pragma unroll
      for (int ni = 0; ni < 4; ++ni) {
        float e = __expf((acc[mi][ni][r] - m) * SC);
        acc[mi][ni][r] = e;
        s += e;
      }
      #pragma unroll
      for (int o = 1; o <= 8; o <<= 1) s += __shfl_xor(s, o);
      rsum[mi][r] = s;
    }
  if (lr == 0) {
    #pragma unroll
    for (int mi = 0; mi < 8; ++mi)
      #pragma unroll
      for (int r = 0; r < 4; ++r)
        reds[(wr * 128 + mi * 16 + lg * 4 + r) * 4 + wc] = rsum[mi][r];
  }
  __syncthreads();

  // ---- write probabilities to attL [256 t][256 s] (XOR-chunk A-fragment layout)
  #pragma unroll
  for (int mi = 0; mi < 8; ++mi)
    #pragma unroll
    for (int r = 0; r < 4; ++r) {
      const int trow = wr * 128 + mi * 16 + lg * 4 + r;
      f32x4 q = *(const f32x4*)&reds[trow * 4];
      const float inv = 1.f / (q[0] + q[1] + q[2] + q[3]);
      const int t7 = trow & 7;
      #pragma unroll
      for (int ni = 0; ni < 4; ++ni) {
        const int cw = ni * 2 + (lr >> 3);
        const int off = trow * 256 + wc * 64 + ((cw ^ t7) << 3) + (lr & 7);
        attL[off] = f2bf(acc[mi][ni][r] * inv);
      }
    }
  __syncthreads();

  // ---- PV with T14 async-STAGE: oT[t][c] = sum_s att[t][s] v[c][s]
  const unsigned short* Vb = V + (size_t)bz * 131072;
  unsigned short* Ob = O + (size_t)bz * 131072;
  const int vrow = tid >> 3;
  const int vgc = (tid & 7) ^ (vrow & 7);
  us8 nv0, nv1;
  auto ldV = [&](int idx) {
    const int ps = idx >> 2, kt = idx & 3;
    const unsigned short* s0 = Vb + (size_t)(ps * 128 + vrow) * 256 + kt * 64 + vgc * 8;
    nv0 = *(const us8*)s0;
    nv1 = *(const us8*)(s0 + (size_t)64 * 256);
  };
  auto stV = [&]() {
    *(us8*)(vbuf + tid * 8) = nv0;
    *(us8*)(vbuf + (512 + tid) * 8) = nv1;
  };
  ldV(0); stV();
  __syncthreads();
  for (int pass = 0; pass < 4; ++pass) {
    f32x4 po[8][2];
    #pragma unroll
    for (int i = 0; i < 8; ++i)
      #pragma unroll
      for (int j = 0; j < 2; ++j) po[i][j] = (f32x4){0.f, 0.f, 0.f, 0.f};
    for (int kt = 0; kt < 4; ++kt) {
      const int idx = pass * 4 + kt;
      if (idx + 1 < 16) ldV(idx + 1);      // issue next slice loads (hidden under MFMA)
      short8 bfv[2][2];
      #pragma unroll
      for (int nj = 0; nj < 2; ++nj) {
        bfv[nj][0] = *(const short8*)(vbuf + (wc * 32 + nj * 16 + lr) * 64 + ko0);
        bfv[nj][1] = *(const short8*)(vbuf + (wc * 32 + nj * 16 + lr) * 64 + ko1);
      }
      __builtin_amdgcn_s_setprio(1);
      #pragma unroll
      for (int mi = 0; mi < 8; ++mi) {
        const int trow = wr * 128 + mi * 16 + lr;
        const int t7 = trow & 7;
        const unsigned short* ap = attL + trow * 256 + kt * 64;
        short8 afv0 = *(const short8*)(ap + ((lg ^ t7) << 3));
        short8 afv1 = *(const short8*)(ap + (((4 + lg) ^ t7) << 3));
        #pragma unroll
        for (int nj = 0; nj < 2; ++nj) {
          po[mi][nj] = __builtin_amdgcn_mfma_f32_16x16x32_bf16(afv0, bfv[nj][0], po[mi][nj], 0, 0, 0);
          po[mi][nj] = __builtin_amdgcn_mfma_f32_16x16x32_bf16(afv1, bfv[nj][1], po[mi][nj], 0, 0, 0);
        }
      }
      __builtin_amdgcn_s_setprio(0);
      __syncthreads();                      // all waves done reading vbuf
      if (idx + 1 < 16) stV();              // write next slice (vmcnt auto-inserted)
      __syncthreads();                      // next slice visible
    }
    #pragma unroll
    for (int mi = 0; mi < 8; ++mi)
      #pragma unroll
      for (int r = 0; r < 4; ++r) {
        const int trow = wr * 128 + mi * 16 + lg * 4 + r;
        #pragma unroll
        for (int nj = 0; nj < 2; ++nj) {
          const int c = pass * 128 + wc * 32 + nj * 16 + lr;
          Ob[(size_t)trow * 512 + c] = f2bf(po[mi][nj][r]);
        }
      }
  }
}

extern "C" void kernel_launch(void* const* d_in, const int* in_sizes, int n_in,
                              void* d_out, int out_size, void* d_ws, size_t ws_size,
                              hipStream_t stream)
{
  const float* x   = (const float*)d_in[0];
  const float* gnw = (const float*)d_in[1];
  const float* gnb = (const float*)d_in[2];
  const float* wq  = (const float*)d_in[3];
  const float* bq  = (const float*)d_in[4];
  const float* wk  = (const float*)d_in[5];
  // bk cancels in softmax
  const float* wv  = (const float*)d_in[7];
  const float* bv  = (const float*)d_in[8];
  const float* wp  = (const float*)d_in[9];
  const float* bp  = (const float*)d_in[10];
  float* out = (float*)d_out;

  char* ws = (char*)d_ws;
  unsigned short* W2T   = (unsigned short*)(ws);                  // [512][512] bf16
  unsigned short* wvb   = (unsigned short*)(ws + 524288);
  unsigned short* wpb   = (unsigned short*)(ws + 1048576);
  unsigned short* wqT   = (unsigned short*)(ws + 1572864);
  unsigned short* wkT   = (unsigned short*)(ws + 2097152);
  float*          w2b   = (float*)(ws + 2621440);
  unsigned short* hT    = (unsigned short*)(ws + 2885632);        // 65536x512 bf16 (reused as oT)
  unsigned short* T1    = (unsigned short*)(ws + 69994496ull);    // 65536x512 bf16
  unsigned short* v     = (unsigned short*)(ws + 137103360ull);   // B*512*256 bf16
  unsigned short* oT    = hT;

  conv_k<<<512, 256, 0, stream>>>(wv, wp, wvb, wpb);
  tk<<<dim3(8, 8, 2), 256, 0, stream>>>(wq, wk, wqT, wkT);
  w2b_k<<<8, 256, 0, stream>>>(wkT, bq, w2b);
  // W2T[d][c] = sum_o wk[o][d]*wq[o][c]
  gemmp_k<128, 128, 4, 256, 2, 8, 0, false, false, false><<<dim3(4, 4, 1), 256, 0, stream>>>(
      wkT, 0, 512, wqT, 0, 512, W2T, 0, 512, nullptr, nullptr);
  gn_k<<<4096, 512, 0, stream>>>(x, gnw, gnb, hT);
  // G1 (flat): T1'[s][d] = hT x W2T^T + w2b[d]
  gemmp_k<256, 256, 8, 512, 4, 8, 2, false, false, true><<<dim3(2, 256, 1), 512, 0, stream>>>(
      hT, 0, 512, W2T, 0, 512, T1, 0, 512, w2b, nullptr);
  // G1b (per-batch, XCD-swizzled, SBA 48KB / 3 blocks-CU): v[b][c][s] = wvb x hT[b]^T + bv
  gemmp_k<128, 128, 4, 256, 2, 8, 1, false, false, false, 1, true, 3><<<dim3(2048, 1, 1), 256, 0, stream>>>(
      wvb, 0, 512, hT, 131072, 512, v, 131072, 256, bv, nullptr);
  // FUSED G2+G3: att in LDS, oT[b] = softmax(T1' hT^T) x v^T
  fused_k<<<dim3(1, 1, 256), 512, 0, stream>>>(T1, hT, v, oT);
  // G4 (per-batch, XCD-swizzled, SBA): out[b][c][s] = wpb x oT[b]^T + bp + x
  gemmp_k<128, 128, 4, 256, 2, 8, 1, true, true, false, 1, true, 3><<<dim3(2048, 1, 1), 256, 0, stream>>>(
      wpb, 0, 512, oT, 131072, 512, out, 131072, 256, bp, x);
}

// Round 14
// 288.288 us; speedup vs baseline: 1.4333x; 1.0422x over previous
//
#include <hip/hip_runtime.h>

typedef __attribute__((ext_vector_type(8))) short short8;
typedef __attribute__((ext_vector_type(8))) unsigned short us8;
typedef __attribute__((ext_vector_type(4))) unsigned short us4;
typedef __attribute__((ext_vector_type(4))) float f32x4;

static __device__ __forceinline__ unsigned short f2bf(float f) {
  union { float f; unsigned u; } c; c.f = f;
  unsigned r = (c.u + 0x7FFFu + ((c.u >> 16) & 1u)) >> 16;
  return (unsigned short)r;
}
static __device__ __forceinline__ float b2f(unsigned short h) {
  union { unsigned u; float f; } c; c.u = ((unsigned)h) << 16; return c.f;
}

static __device__ __forceinline__ void gll16(const unsigned short* g, unsigned short* l) {
  __builtin_amdgcn_global_load_lds(
      (const __attribute__((address_space(1))) unsigned int*)g,
      (__attribute__((address_space(3))) unsigned int*)l, 16, 0, 0);
}

// ---- wp -> bf16
__global__ __launch_bounds__(256) void conv_k(
    const float* __restrict__ wp, unsigned short* __restrict__ wpb)
{
  int i4 = (blockIdx.x * 256 + threadIdx.x) * 4;
  f32x4 v = *(const f32x4*)(wp + i4);
  us4 o;
  #pragma unroll
  for (int j = 0; j < 4; ++j) o[j] = f2bf(v[j]);
  *(us4*)(wpb + i4) = o;
}

// ---- transpose wq,wk,wv (f32 [512][512]) -> bf16 [c][o]
__global__ __launch_bounds__(256) void tk(
    const float* __restrict__ wq, const float* __restrict__ wk,
    const float* __restrict__ wv,
    unsigned short* __restrict__ wqT, unsigned short* __restrict__ wkT,
    unsigned short* __restrict__ wvT)
{
  __shared__ float L[64][65];
  const float* src = blockIdx.z == 0 ? wq : (blockIdx.z == 1 ? wk : wv);
  unsigned short* dst = blockIdx.z == 0 ? wqT : (blockIdx.z == 1 ? wkT : wvT);
  const int ro = blockIdx.x * 64, co = blockIdx.y * 64;
  const int tid = threadIdx.x;
  #pragma unroll
  for (int p = 0; p < 4; ++p) {
    int lin = p * 1024 + tid * 4;
    int r = lin >> 6, cl = lin & 63;
    *(f32x4*)&L[r][cl] = *(const f32x4*)(src + (size_t)(ro + r) * 512 + co + cl);
  }
  __syncthreads();
  #pragma unroll
  for (int p = 0; p < 4; ++p) {
    int lin = p * 1024 + tid * 4;
    int rr = lin >> 6, cc = lin & 63;
    us4 o;
    #pragma unroll
    for (int j = 0; j < 4; ++j) o[j] = f2bf(L[cc + j][rr]);
    *(us4*)(dst + (size_t)(co + rr) * 512 + ro + cc) = o;
  }
}

// ---- w2b[c] = sum_o bq[o] * wk[o][c]
__global__ __launch_bounds__(256) void w2b_k(
    const unsigned short* __restrict__ wkT, const float* __restrict__ bq,
    float* __restrict__ w2b)
{
  const int wv_ = threadIdx.x >> 6, lane = threadIdx.x & 63;
  for (int i = 0; i < 16; ++i) {
    const int c = blockIdx.x * 64 + i * 4 + wv_;
    us8 kv = *(const us8*)(wkT + (size_t)c * 512 + lane * 8);
    float s = 0.f;
    #pragma unroll
    for (int j = 0; j < 8; ++j) s += b2f(kv[j]) * bq[lane * 8 + j];
    #pragma unroll
    for (int o = 32; o; o >>= 1) s += __shfl_xor(s, o);
    if (lane == 0) w2b[c] = s;
  }
}

// ---- bfold[c] = sum_m wp[c][m]*bv[m] + bp[c]  (exact f32)
__global__ __launch_bounds__(256) void bfold_k(
    const float* __restrict__ wp, const float* __restrict__ bv,
    const float* __restrict__ bp, float* __restrict__ bfold)
{
  const int wv_ = threadIdx.x >> 6, lane = threadIdx.x & 63;
  for (int i = 0; i < 16; ++i) {
    const int c = blockIdx.x * 64 + i * 4 + wv_;
    const float* row = wp + (size_t)c * 512 + lane * 8;
    f32x4 a0 = *(const f32x4*)row;
    f32x4 a1 = *(const f32x4*)(row + 4);
    f32x4 b0 = *(const f32x4*)(bv + lane * 8);
    f32x4 b1 = *(const f32x4*)(bv + lane * 8 + 4);
    float s = a0[0]*b0[0] + a0[1]*b0[1] + a0[2]*b0[2] + a0[3]*b0[3]
            + a1[0]*b1[0] + a1[1]*b1[1] + a1[2]*b1[2] + a1[3]*b1[3];
    #pragma unroll
    for (int o = 32; o; o >>= 1) s += __shfl_xor(s, o);
    if (lane == 0) bfold[c] = s + bp[c];
  }
}

// ---- GroupNorm -> hT [b][s][c] bf16 AND h [b][c][s] bf16
__global__ __launch_bounds__(512) void gn_k(
    const float* __restrict__ x, const float* __restrict__ gw,
    const float* __restrict__ gb, unsigned short* __restrict__ hT,
    unsigned short* __restrict__ h)
{
  __shared__ unsigned short tile[32][256];
  __shared__ float rs[2][4][2];
  const int b = blockIdx.x >> 4, gp = blockIdx.x & 15;
  const int tid = threadIdx.x;
  const int sub = tid >> 8;
  const int t = tid & 255;
  const int g = gp * 2 + sub;
  const float* xp = x + ((size_t)b * 512 + g * 16) * 256;
  f32x4 vals[4];
  float s = 0.f, s2 = 0.f;
  #pragma unroll
  for (int j = 0; j < 4; ++j) {
    f32x4 v = *(const f32x4*)(xp + j * 1024 + t * 4);
    vals[j] = v;
    s  += v[0] + v[1] + v[2] + v[3];
    s2 += v[0]*v[0] + v[1]*v[1] + v[2]*v[2] + v[3]*v[3];
  }
  #pragma unroll
  for (int o = 32; o; o >>= 1) { s += __shfl_xor(s, o); s2 += __shfl_xor(s2, o); }
  if ((t & 63) == 0) { rs[sub][t >> 6][0] = s; rs[sub][t >> 6][1] = s2; }
  __syncthreads();
  s  = rs[sub][0][0] + rs[sub][1][0] + rs[sub][2][0] + rs[sub][3][0];
  s2 = rs[sub][0][1] + rs[sub][1][1] + rs[sub][2][1] + rs[sub][3][1];
  const float mean = s * (1.f / 4096.f);
  const float var  = s2 * (1.f / 4096.f) - mean * mean;
  const float rstd = rsqrtf(var + 1e-5f);
  #pragma unroll
  for (int j = 0; j < 4; ++j) {
    const int cl = j * 4 + (t >> 6);
    const int c = g * 16 + cl;
    const float sc = gw[c] * rstd;
    const float sh = gb[c] - mean * sc;
    f32x4 v = vals[j];
    us4 o;
    #pragma unroll
    for (int q = 0; q < 4; ++q) o[q] = f2bf(v[q] * sc + sh);
    *(us4*)&tile[sub * 16 + cl][(t & 63) * 4] = o;
    *(us4*)(h + ((size_t)b * 512 + c) * 256 + (t & 63) * 4) = o;
  }
  __syncthreads();
  const int srow = tid >> 1, half = tid & 1;
  us8 o0, o1;
  #pragma unroll
  for (int c = 0; c < 8; ++c) o0[c] = tile[half * 16 + c][srow];
  #pragma unroll
  for (int c = 0; c < 8; ++c) o1[c] = tile[half * 16 + 8 + c][srow];
  unsigned short* dst = hT + ((size_t)b * 256 + srow) * 512 + gp * 32 + half * 16;
  *(us8*)dst = o0;
  *(us8*)(dst + 8) = o1;
}

// ---- pipelined B^T-form GEMM: C[bz][m][n] = sum_k A[m][k]*B[n][k] (+bias)(+resid)
// SWZ=1: 1D grid 2048; all 8 blocks of a batch bound to one XCD (L&7).
template<int BM, int BN, int MI, int TPB, int NWN, int NTT,
         int BIAS_MODE, bool OUT_F32, bool HAS_RESID, bool NFAST, int SWZ = 0>
__global__ __launch_bounds__(TPB, 2) void gemmp_k(
    const unsigned short* __restrict__ A, long long sAb, int lda,
    const unsigned short* __restrict__ B, long long sBb, int ldb,
    void* __restrict__ Cv, long long sCb, int ldc,
    const float* __restrict__ bias, const float* __restrict__ resid)
{
  constexpr int CA = BM * 8 / TPB;
  constexpr int CB = BN * 8 / TPB;
  __shared__ unsigned short SMEM[2 * BM * 64 + 2 * BN * 64];
  unsigned short* AsBase = SMEM;
  unsigned short* BsBase = SMEM + 2 * BM * 64;
  const int tid = threadIdx.x;
  int bz, bm, bn;
  if (SWZ) {
    const int L = blockIdx.x;
    const int xcd = L & 7, j = (L >> 3) & 7, bhi = L >> 6;
    bz = bhi * 8 + xcd;
    bm = (j >> 1) * BM;
    bn = (j & 1) * BN;
  } else {
    bz = blockIdx.z;
    bm = (NFAST ? blockIdx.y : blockIdx.x) * BM;
    bn = (NFAST ? blockIdx.x : blockIdx.y) * BN;
  }
  const int lane = tid & 63, w = tid >> 6;
  const int wr = w / NWN, wc = w % NWN;
  const int lr = lane & 15, lg = lane >> 4;
  const int csw = lr & 7;
  const int ko0 = (lg ^ csw) * 8;
  const int ko1 = ((4 + lg) ^ csw) * 8;

  const unsigned short* aSrc[CA]; int aOff[CA];
  #pragma unroll
  for (int p = 0; p < CA; ++p) {
    const int id = p * TPB + tid;
    const int row = id >> 3, cc = (id & 7) ^ (row & 7);
    aSrc[p] = A + (size_t)bz * sAb + (size_t)(bm + row) * lda + cc * 8;
    aOff[p] = id * 8;
  }
  const unsigned short* bSrc[CB]; int bOff[CB];
  #pragma unroll
  for (int p = 0; p < CB; ++p) {
    const int id = p * TPB + tid;
    const int row = id >> 3, cc = (id & 7) ^ (row & 7);
    bSrc[p] = B + (size_t)bz * sBb + (size_t)(bn + row) * ldb + cc * 8;
    bOff[p] = id * 8;
  }

  f32x4 acc[MI][4];
  #pragma unroll
  for (int i = 0; i < MI; ++i)
    #pragma unroll
    for (int j = 0; j < 4; ++j) acc[i][j] = (f32x4){0.f, 0.f, 0.f, 0.f};

  #pragma unroll
  for (int p = 0; p < CA; ++p) gll16(aSrc[p], &AsBase[aOff[p]]);
  #pragma unroll
  for (int p = 0; p < CB; ++p) gll16(bSrc[p], &BsBase[bOff[p]]);
  asm volatile("s_waitcnt vmcnt(0)" ::: "memory");
  __builtin_amdgcn_s_barrier();

  #pragma unroll 2
  for (int t = 0; t < NTT; ++t) {
    if (t + 1 < NTT) {
      const int k1 = (t + 1) * 64, sl = (t + 1) & 1;
      #pragma unroll
      for (int p = 0; p < CA; ++p) gll16(aSrc[p] + k1, &AsBase[sl * BM * 64 + aOff[p]]);
      #pragma unroll
      for (int p = 0; p < CB; ++p) gll16(bSrc[p] + k1, &BsBase[sl * BN * 64 + bOff[p]]);
    }
    const unsigned short* At = &AsBase[(t & 1) * BM * 64];
    const unsigned short* Bt = &BsBase[(t & 1) * BN * 64];
    short8 bf[4][2];
    #pragma unroll
    for (int nj = 0; nj < 4; ++nj) {
      bf[nj][0] = *(const short8*)(Bt + (wc * 64 + nj * 16 + lr) * 64 + ko0);
      bf[nj][1] = *(const short8*)(Bt + (wc * 64 + nj * 16 + lr) * 64 + ko1);
    }
    #pragma unroll
    for (int h = 0; h < MI / 4; ++h) {
      short8 af[4][2];
      #pragma unroll
      for (int mi = 0; mi < 4; ++mi) {
        const int rr = wr * (MI * 16) + h * 64 + mi * 16 + lr;
        af[mi][0] = *(const short8*)(At + rr * 64 + ko0);
        af[mi][1] = *(const short8*)(At + rr * 64 + ko1);
      }
      __builtin_amdgcn_s_setprio(1);
      #pragma unroll
      for (int mi = 0; mi < 4; ++mi)
        #pragma unroll
        for (int nj = 0; nj < 4; ++nj) {
          acc[h * 4 + mi][nj] = __builtin_amdgcn_mfma_f32_16x16x32_bf16(af[mi][0], bf[nj][0], acc[h * 4 + mi][nj], 0, 0, 0);
          acc[h * 4 + mi][nj] = __builtin_amdgcn_mfma_f32_16x16x32_bf16(af[mi][1], bf[nj][1], acc[h * 4 + mi][nj], 0, 0, 0);
        }
      __builtin_amdgcn_s_setprio(0);
    }
    if (t + 1 < NTT) {
      asm volatile("s_waitcnt vmcnt(0)" ::: "memory");
      __builtin_amdgcn_s_barrier();
    }
  }

  #pragma unroll
  for (int mi = 0; mi < MI; ++mi) {
    #pragma unroll
    for (int r = 0; r < 4; ++r) {
      const int rowc = bm + wr * (MI * 16) + mi * 16 + lg * 4 + r;
      const float bv_ = (BIAS_MODE == 1) ? bias[rowc] : 0.f;
      #pragma unroll
      for (int ni = 0; ni < 4; ++ni) {
        const int col = bn + wc * 64 + ni * 16 + lr;
        float vv = acc[mi][ni][r] + bv_;
        if (BIAS_MODE == 2) vv += bias[col];
        const size_t idx = (size_t)bz * sCb + (size_t)rowc * ldc + col;
        if (HAS_RESID) vv += resid[idx];
        if (OUT_F32) ((float*)Cv)[idx] = vv;
        else ((unsigned short*)Cv)[idx] = f2bf(vv);
      }
    }
  }
}

// ---- FUSED G2+G3: att = softmax(T1' hT^T / sqrt(512)) in LDS, then y = att x h^T.
__global__ __launch_bounds__(512, 1) void fused_k(
    const unsigned short* __restrict__ A,   // T1' [b][256][512]
    const unsigned short* __restrict__ B,   // hT  [b][256][512]
    const unsigned short* __restrict__ V,   // h   [b][512][256]
    unsigned short* __restrict__ O)         // y   [b][256][512]
{
  __shared__ __attribute__((aligned(16))) char SM[147456];   // 144 KB
  unsigned short* AsB = (unsigned short*)SM;
  unsigned short* BsB = (unsigned short*)(SM + 65536);
  unsigned short* attL = (unsigned short*)SM;
  unsigned short* vbuf = (unsigned short*)(SM + 131072);
  float* redm = (float*)(SM + 131072);
  float* reds = redm + 1024;

  const int tid = threadIdx.x;
  const int bz = blockIdx.z;
  const int lane = tid & 63, w = tid >> 6;
  const int wr = w >> 2, wc = w & 3;
  const int lr = lane & 15, lg = lane >> 4;
  const int csw = lr & 7;
  const int ko0 = (lg ^ csw) * 8;
  const int ko1 = ((4 + lg) ^ csw) * 8;

  const int rl = tid >> 3;
  const int gc = (tid & 7) ^ (rl & 7);
  const unsigned short* pA = A + (size_t)bz * 131072 + (size_t)rl * 512 + gc * 8;
  const unsigned short* pB = B + (size_t)bz * 131072 + (size_t)rl * 512 + gc * 8;

  auto stageA = [&](int t, int h) {
    const unsigned short* s = pA + (size_t)h * 65536 + t * 64;
    unsigned short* d = AsB + ((2 * t + h) & 3) * 8192 + tid * 8;
    gll16(s, d);
    gll16(s + 32768, d + 4096);
  };
  auto stageB = [&](int t, int h) {
    const unsigned short* s = pB + (size_t)h * 65536 + t * 64;
    unsigned short* d = BsB + ((2 * t + h) & 3) * 8192 + tid * 8;
    gll16(s, d);
    gll16(s + 32768, d + 4096);
  };

  f32x4 acc[8][4];
  #pragma unroll
  for (int i = 0; i < 8; ++i)
    #pragma unroll
    for (int j = 0; j < 4; ++j) acc[i][j] = (f32x4){0.f, 0.f, 0.f, 0.f};

  stageA(0, 0); stageA(0, 1); stageB(0, 0); stageB(0, 1);
  stageB(1, 0); stageA(1, 0); stageA(1, 1);
  asm volatile("s_waitcnt vmcnt(6)" ::: "memory");
  __builtin_amdgcn_s_barrier();

  constexpr int NT = 8;
  for (int t = 0; t < NT; ++t) {
    const unsigned short* sA = AsB + ((2 * t + wr) & 3) * 8192;
    const unsigned short* sB = BsB + ((2 * t + (wc >> 1)) & 3) * 8192;
    const int bc = (wc & 1) * 64;
    short8 af[4][2], bf0[2][2], bf1[2][2];

    #pragma unroll
    for (int mi = 0; mi < 4; ++mi) {
      af[mi][0] = *(const short8*)(sA + (mi * 16 + lr) * 64 + ko0);
      af[mi][1] = *(const short8*)(sA + (mi * 16 + lr) * 64 + ko1);
    }
    #pragma unroll
    for (int nj = 0; nj < 2; ++nj) {
      bf0[nj][0] = *(const short8*)(sB + (bc + nj * 16 + lr) * 64 + ko0);
      bf0[nj][1] = *(const short8*)(sB + (bc + nj * 16 + lr) * 64 + ko1);
    }
    if (t + 1 < NT) stageB(t + 1, 1);
    __builtin_amdgcn_s_barrier();
    __builtin_amdgcn_s_setprio(1);
    #pragma unroll
    for (int mi = 0; mi < 4; ++mi)
      #pragma unroll
      for (int nj = 0; nj < 2; ++nj) {
        acc[mi][nj] = __builtin_amdgcn_mfma_f32_16x16x32_bf16(af[mi][0], bf0[nj][0], acc[mi][nj], 0, 0, 0);
        acc[mi][nj] = __builtin_amdgcn_mfma_f32_16x16x32_bf16(af[mi][1], bf0[nj][1], acc[mi][nj], 0, 0, 0);
      }
    __builtin_amdgcn_s_setprio(0);
    __builtin_amdgcn_s_barrier();

    #pragma unroll
    for (int nj = 0; nj < 2; ++nj) {
      bf1[nj][0] = *(const short8*)(sB + (bc + 32 + nj * 16 + lr) * 64 + ko0);
      bf1[nj][1] = *(const short8*)(sB + (bc + 32 + nj * 16 + lr) * 64 + ko1);
    }
    __builtin_amdgcn_s_barrier();
    __builtin_amdgcn_s_setprio(1);
    #pragma unroll
    for (int mi = 0; mi < 4; ++mi)
      #pragma unroll
      for (int nj = 0; nj < 2; ++nj) {
        acc[mi][2 + nj] = __builtin_amdgcn_mfma_f32_16x16x32_bf16(af[mi][0], bf1[nj][0], acc[mi][2 + nj], 0, 0, 0);
        acc[mi][2 + nj] = __builtin_amdgcn_mfma_f32_16x16x32_bf16(af[mi][1], bf1[nj][1], acc[mi][2 + nj], 0, 0, 0);
      }
    __builtin_amdgcn_s_setprio(0);
    __builtin_amdgcn_s_barrier();

    #pragma unroll
    for (int mi = 0; mi < 4; ++mi) {
      af[mi][0] = *(const short8*)(sA + (64 + mi * 16 + lr) * 64 + ko0);
      af[mi][1] = *(const short8*)(sA + (64 + mi * 16 + lr) * 64 + ko1);
    }
    if (t + 2 < NT) stageB(t + 2, 0);
    __builtin_amdgcn_s_barrier();
    __builtin_amdgcn_s_setprio(1);
    #pragma unroll
    for (int mi = 0; mi < 4; ++mi)
      #pragma unroll
      for (int nj = 0; nj < 2; ++nj) {
        acc[4 + mi][nj] = __builtin_amdgcn_mfma_f32_16x16x32_bf16(af[mi][0], bf0[nj][0], acc[4 + mi][nj], 0, 0, 0);
        acc[4 + mi][nj] = __builtin_amdgcn_mfma_f32_16x16x32_bf16(af[mi][1], bf0[nj][1], acc[4 + mi][nj], 0, 0, 0);
      }
    __builtin_amdgcn_s_setprio(0);
    __builtin_amdgcn_s_barrier();

    if (t + 2 < NT) { stageA(t + 2, 0); stageA(t + 2, 1); }
    __builtin_amdgcn_s_barrier();
    __builtin_amdgcn_s_setprio(1);
    #pragma unroll
    for (int mi = 0; mi < 4; ++mi)
      #pragma unroll
      for (int nj = 0; nj < 2; ++nj) {
        acc[4 + mi][2 + nj] = __builtin_amdgcn_mfma_f32_16x16x32_bf16(af[mi][0], bf1[nj][0], acc[4 + mi][2 + nj], 0, 0, 0);
        acc[4 + mi][2 + nj] = __builtin_amdgcn_mfma_f32_16x16x32_bf16(af[mi][1], bf1[nj][1], acc[4 + mi][2 + nj], 0, 0, 0);
      }
    __builtin_amdgcn_s_setprio(0);
    if (t == NT - 2)      asm volatile("s_waitcnt vmcnt(0)" ::: "memory");
    else if (t < NT - 2)  asm volatile("s_waitcnt vmcnt(6)" ::: "memory");
    __builtin_amdgcn_s_barrier();
  }

  // ---- softmax
  const float SC = 0.044194173824159216f;
  float rmax[8][4];
  #pragma unroll
  for (int mi = 0; mi < 8; ++mi)
    #pragma unroll
    for (int r = 0; r < 4; ++r) {
      float m = fmaxf(fmaxf(acc[mi][0][r], acc[mi][1][r]),
                      fmaxf(acc[mi][2][r], acc[mi][3][r]));
      #pragma unroll
      for (int o = 1; o <= 8; o <<= 1) m = fmaxf(m, __shfl_xor(m, o));
      rmax[mi][r] = m;
    }
  __syncthreads();
  if (lr == 0) {
    #pragma unroll
    for (int mi = 0; mi < 8; ++mi)
      #pragma unroll
      for (int r = 0; r < 4; ++r)
        redm[(wr * 128 + mi * 16 + lg * 4 + r) * 4 + wc] = rmax[mi][r];
  }
  __syncthreads();
  float rsum[8][4];
  #pragma unroll
  for (int mi = 0; mi < 8; ++mi)
    #pragma unroll
    for (int r = 0; r < 4; ++r) {
      const int row = wr * 128 + mi * 16 + lg * 4 + r;
      f32x4 q = *(const f32x4*)&redm[row * 4];
      const float m = fmaxf(fmaxf(q[0], q[1]), fmaxf(q[2], q[3]));
      float s = 0.f;
      #pragma unroll
      for (int ni = 0; ni < 4; ++ni) {
        float e = __expf((acc[mi][ni][r] - m) * SC);
        acc[mi][ni][r] = e;
        s += e;
      }
      #pragma unroll
      for (int o = 1; o <= 8; o <<= 1) s += __shfl_xor(s, o);
      rsum[mi][r] = s;
    }
  if (lr == 0) {
    #pragma unroll
    for (int mi = 0; mi < 8; ++mi)
      #pragma unroll
      for (int r = 0; r < 4; ++r)
        reds[(wr * 128 + mi * 16 + lg * 4 + r) * 4 + wc] = rsum[mi][r];
  }
  __syncthreads();

  // ---- write probabilities to attL [256 t][256 s] (XOR-chunk A-fragment layout)
  #pragma unroll
  for (int mi = 0; mi < 8; ++mi)
    #pragma unroll
    for (int r = 0; r < 4; ++r) {
      const int trow = wr * 128 + mi * 16 + lg * 4 + r;
      f32x4 q = *(const f32x4*)&reds[trow * 4];
      const float inv = 1.f / (q[0] + q[1] + q[2] + q[3]);
      const int t7 = trow & 7;
      #pragma unroll
      for (int ni = 0; ni < 4; ++ni) {
        const int cw = ni * 2 + (lr >> 3);
        const int off = trow * 256 + wc * 64 + ((cw ^ t7) << 3) + (lr & 7);
        attL[off] = f2bf(acc[mi][ni][r] * inv);
      }
    }
  __syncthreads();

  // ---- PV with T14 async-STAGE: y[t][c] = sum_s att[t][s] h[c][s]
  const unsigned short* Vb = V + (size_t)bz * 131072;
  unsigned short* Ob = O + (size_t)bz * 131072;
  const int vrow = tid >> 3;
  const int vgc = (tid & 7) ^ (vrow & 7);
  us8 nv0, nv1;
  auto ldV = [&](int idx) {
    const int ps = idx >> 2, kt = idx & 3;
    const unsigned short* s0 = Vb + (size_t)(ps * 128 + vrow) * 256 + kt * 64 + vgc * 8;
    nv0 = *(const us8*)s0;
    nv1 = *(const us8*)(s0 + (size_t)64 * 256);
  };
  auto stV = [&]() {
    *(us8*)(vbuf + tid * 8) = nv0;
    *(us8*)(vbuf + (512 + tid) * 8) = nv1;
  };
  ldV(0); stV();
  __syncthreads();
  for (int pass = 0; pass < 4; ++pass) {
    f32x4 po[8][2];
    #pragma unroll
    for (int i = 0; i < 8; ++i)
      #pragma unroll
      for (int j = 0; j < 2; ++j) po[i][j] = (f32x4){0.f, 0.f, 0.f, 0.f};
    for (int kt = 0; kt < 4; ++kt) {
      const int idx = pass * 4 + kt;
      if (idx + 1 < 16) ldV(idx + 1);
      short8 bfv[2][2];
      #pragma unroll
      for (int nj = 0; nj < 2; ++nj) {
        bfv[nj][0] = *(const short8*)(vbuf + (wc * 32 + nj * 16 + lr) * 64 + ko0);
        bfv[nj][1] = *(const short8*)(vbuf + (wc * 32 + nj * 16 + lr) * 64 + ko1);
      }
      __builtin_amdgcn_s_setprio(1);
      #pragma unroll
      for (int mi = 0; mi < 8; ++mi) {
        const int trow = wr * 128 + mi * 16 + lr;
        const int t7 = trow & 7;
        const unsigned short* ap = attL + trow * 256 + kt * 64;
        short8 afv0 = *(const short8*)(ap + ((lg ^ t7) << 3));
        short8 afv1 = *(const short8*)(ap + (((4 + lg) ^ t7) << 3));
        #pragma unroll
        for (int nj = 0; nj < 2; ++nj) {
          po[mi][nj] = __builtin_amdgcn_mfma_f32_16x16x32_bf16(afv0, bfv[nj][0], po[mi][nj], 0, 0, 0);
          po[mi][nj] = __builtin_amdgcn_mfma_f32_16x16x32_bf16(afv1, bfv[nj][1], po[mi][nj], 0, 0, 0);
        }
      }
      __builtin_amdgcn_s_setprio(0);
      __syncthreads();
      if (idx + 1 < 16) stV();
      __syncthreads();
    }
    #pragma unroll
    for (int mi = 0; mi < 8; ++mi)
      #pragma unroll
      for (int r = 0; r < 4; ++r) {
        const int trow = wr * 128 + mi * 16 + lg * 4 + r;
        #pragma unroll
        for (int nj = 0; nj < 2; ++nj) {
          const int c = pass * 128 + wc * 32 + nj * 16 + lr;
          Ob[(size_t)trow * 512 + c] = f2bf(po[mi][nj][r]);
        }
      }
  }
}

extern "C" void kernel_launch(void* const* d_in, const int* in_sizes, int n_in,
                              void* d_out, int out_size, void* d_ws, size_t ws_size,
                              hipStream_t stream)
{
  const float* x   = (const float*)d_in[0];
  const float* gnw = (const float*)d_in[1];
  const float* gnb = (const float*)d_in[2];
  const float* wq  = (const float*)d_in[3];
  const float* bq  = (const float*)d_in[4];
  const float* wk  = (const float*)d_in[5];
  // bk cancels in softmax
  const float* wv  = (const float*)d_in[7];
  const float* bv  = (const float*)d_in[8];
  const float* wp  = (const float*)d_in[9];
  const float* bp  = (const float*)d_in[10];
  float* out = (float*)d_out;

  char* ws = (char*)d_ws;
  unsigned short* W2T   = (unsigned short*)(ws);                  // [512][512] bf16
  unsigned short* wvT   = (unsigned short*)(ws + 524288);
  unsigned short* wpb   = (unsigned short*)(ws + 1048576);
  unsigned short* wqT   = (unsigned short*)(ws + 1572864);
  unsigned short* wkT   = (unsigned short*)(ws + 2097152);
  float*          w2b   = (float*)(ws + 2621440);
  float*          bfold = (float*)(ws + 2623488);
  unsigned short* Wpvb  = (unsigned short*)(ws + 2625536);        // [512][512] bf16
  unsigned short* hT    = (unsigned short*)(ws + 3276800);        // 65536x512 bf16 (reused as y)
  unsigned short* T1    = (unsigned short*)(ws + 70385664ull);    // 65536x512 bf16
  unsigned short* h     = (unsigned short*)(ws + 137494528ull);   // B*512*256 bf16
  unsigned short* yT    = hT;

  conv_k<<<256, 256, 0, stream>>>(wp, wpb);
  tk<<<dim3(8, 8, 3), 256, 0, stream>>>(wq, wk, wv, wqT, wkT, wvT);
  w2b_k<<<8, 256, 0, stream>>>(wkT, bq, w2b);
  bfold_k<<<8, 256, 0, stream>>>(wp, bv, bp, bfold);
  // W2T[d][c] = sum_o wk[o][d]*wq[o][c]
  gemmp_k<128, 128, 4, 256, 2, 8, 0, false, false, false><<<dim3(4, 4, 1), 256, 0, stream>>>(
      wkT, 0, 512, wqT, 0, 512, W2T, 0, 512, nullptr, nullptr);
  // Wpv[c][c'] = sum_m wp[c][m]*wv[m][c']  (A=wpb rows c, B=wvT rows c')
  gemmp_k<128, 128, 4, 256, 2, 8, 0, false, false, false><<<dim3(4, 4, 1), 256, 0, stream>>>(
      wpb, 0, 512, wvT, 0, 512, Wpvb, 0, 512, nullptr, nullptr);
  gn_k<<<4096, 512, 0, stream>>>(x, gnw, gnb, hT, h);
  // G1 (flat): T1'[s][d] = hT x W2T^T + w2b[d]
  gemmp_k<256, 256, 8, 512, 4, 8, 2, false, false, true><<<dim3(2, 256, 1), 512, 0, stream>>>(
      hT, 0, 512, W2T, 0, 512, T1, 0, 512, w2b, nullptr);
  // FUSED G2+G3: att in LDS, y[b][t][c] = softmax(T1' hT^T) x h^T
  fused_k<<<dim3(1, 1, 256), 512, 0, stream>>>(T1, hT, h, yT);
  // G4 (per-batch, XCD-swizzled): out[b][c][s] = Wpv x y[b]^T + bfold + x
  gemmp_k<128, 128, 4, 256, 2, 8, 1, true, true, false, 1><<<dim3(2048, 1, 1), 256, 0, stream>>>(
      Wpvb, 0, 512, yT, 131072, 512, out, 131072, 256, bfold, x);
}